// Round 4
// baseline (203.476 us; speedup 1.0000x reference)
//
#include <hip/hip_runtime.h>
#include <hip/hip_bf16.h>

#define CCH 256
#define CQK 32
#define NHW 4096

typedef float f32x4 __attribute__((ext_vector_type(4)));
typedef _Float16 hv8 __attribute__((ext_vector_type(8)));
typedef _Float16 hv4 __attribute__((ext_vector_type(4)));
typedef __fp16 fv2 __attribute__((ext_vector_type(2)));   // cvt_pkrtz native type

// Monotone float<->uint encoding so float max == uint max (handles negatives).
__device__ __forceinline__ unsigned enc_f32(float f) {
    unsigned u = __float_as_uint(f);
    return (u & 0x80000000u) ? ~u : (u | 0x80000000u);
}
__device__ __forceinline__ float dec_f32(unsigned u) {
    return __uint_as_float((u & 0x80000000u) ? (u ^ 0x80000000u) : ~u);
}

// ---------------------------------------------------------------------------
// Prep kernel: (a) convert Wall = concat(b_w, c_w, d_w) fp32 -> fp16 [320][256];
// b_w rows prescaled by log2(e) so QK^T comes out in exp2 units.
// (b) init m_enc = 0. Grid 144 x 256.
// ---------------------------------------------------------------------------
__global__ __launch_bounds__(256) void prep_kernel(
    const float* __restrict__ b_w, const float* __restrict__ c_w,
    const float* __restrict__ d_w, _Float16* __restrict__ Wh,
    unsigned* __restrict__ m_enc)
{
    const int bid = blockIdx.x, tid = threadIdx.x;
    if (bid < 80) {
        const int idx = (bid * 256 + tid) * 4;
        const int row = idx >> 8, col = idx & 255;
        const float* src = (row < 32) ? (b_w + row * CCH + col)
                         : (row < 64) ? (c_w + (row - 32) * CCH + col)
                                      : (d_w + (row - 64) * CCH + col);
        const float scl = (row < 32) ? 1.4426950408889634f : 1.0f;
        float4 v = *reinterpret_cast<const float4*>(src);
        _Float16* dst = Wh + (size_t)row * CCH + col;
        dst[0] = (_Float16)(v.x * scl); dst[1] = (_Float16)(v.y * scl);
        dst[2] = (_Float16)(v.z * scl); dst[3] = (_Float16)(v.w * scl);
    } else {
        m_enc[(bid - 80) * 256 + tid] = 0u;
    }
}

// ---------------------------------------------------------------------------
// Projection kernel (round-6/7 verified structure, unchanged).
// ---------------------------------------------------------------------------
__global__ __launch_bounds__(256) void proj_kernel(
    const float* __restrict__ a, const _Float16* __restrict__ Wh,
    const float* __restrict__ b_b, const float* __restrict__ c_b,
    const float* __restrict__ d_b,
    _Float16* __restrict__ bqT, _Float16* __restrict__ ckT,
    _Float16* __restrict__ dv)
{
    __shared__ _Float16 aT[32][CCH + 24];

    const int n    = blockIdx.x >> 7;
    const int i0   = (blockIdx.x & 127) << 5;
    const int tid  = threadIdx.x;
    const int lane = tid & 63;
    const int wave = tid >> 6;
    const int l15  = lane & 15;
    const int quad = lane >> 4;

    {
        const float* ap = a + (size_t)(n*CCH + tid)*NHW + i0;
        #pragma unroll
        for (int j = 0; j < 8; ++j) {
            float4 v = *reinterpret_cast<const float4*>(ap + j*4);
            aT[j*4+0][tid] = (_Float16)v.x;
            aT[j*4+1][tid] = (_Float16)v.y;
            aT[j*4+2][tid] = (_Float16)v.z;
            aT[j*4+3][tid] = (_Float16)v.w;
        }
    }
    __syncthreads();

    const f32x4 zf = {0.f, 0.f, 0.f, 0.f};
    f32x4 acc[5][2];
    #pragma unroll
    for (int t = 0; t < 5; ++t) { acc[t][0] = zf; acc[t][1] = zf; }

    const int ch0w = wave * 80;

    #pragma unroll
    for (int ks = 0; ks < 8; ++ks) {
        const int k0 = ks * 32;
        hv8 af0 = *reinterpret_cast<const hv8*>(&aT[l15][k0 + quad*8]);
        hv8 af1 = *reinterpret_cast<const hv8*>(&aT[16 + l15][k0 + quad*8]);
        #pragma unroll
        for (int t = 0; t < 5; ++t) {
            const int ch0 = ch0w + t*16;
            hv8 bf = *reinterpret_cast<const hv8*>(
                Wh + (size_t)(ch0 + l15)*CCH + k0 + quad*8);
            acc[t][0] = __builtin_amdgcn_mfma_f32_16x16x32_f16(af0, bf, acc[t][0], 0, 0, 0);
            acc[t][1] = __builtin_amdgcn_mfma_f32_16x16x32_f16(af1, bf, acc[t][1], 0, 0, 0);
        }
    }

    const int pos_b = i0 + quad*4;
    #pragma unroll
    for (int t = 0; t < 5; ++t) {
        const int ch0 = ch0w + t*16;
        if (ch0 < 64) {
            const float* bias_arr = (ch0 < 32) ? b_b : c_b;
            _Float16*    outp     = (ch0 < 32) ? bqT : ckT;
            const int    ch       = (ch0 & 31) + l15;
            const float  bias     = bias_arr[ch] *
                ((ch0 < 32) ? 1.4426950408889634f : 1.0f);
            #pragma unroll
            for (int nf = 0; nf < 2; ++nf) {
                #pragma unroll
                for (int r = 0; r < 4; ++r) {
                    const int pos = pos_b + nf*16 + r;
                    outp[((size_t)n*NHW + pos)*CQK + ch] =
                        (_Float16)(acc[t][nf][r] + bias);
                }
            }
        } else {
            const int ch   = ch0 - 64 + l15;
            const float bias = d_b[ch];
            #pragma unroll
            for (int nf = 0; nf < 2; ++nf) {
                hv4 v = { (_Float16)(acc[t][nf][0] + bias),
                          (_Float16)(acc[t][nf][1] + bias),
                          (_Float16)(acc[t][nf][2] + bias),
                          (_Float16)(acc[t][nf][3] + bias) };
                *reinterpret_cast<hv4*>(
                    dv + ((size_t)n*CCH + ch)*NHW + pos_b + nf*16) = v;
            }
        }
    }
}

// ---------------------------------------------------------------------------
// Pass A: per-q-row max of the (log2e-scaled) scores. Unchanged.
// ---------------------------------------------------------------------------
__global__ __launch_bounds__(256) void rowmax_kernel(
    const _Float16* __restrict__ bqT, const _Float16* __restrict__ ckT,
    unsigned* __restrict__ m_enc)
{
    const int bx   = blockIdx.x;
    const int n    = bx >> 8;
    const int qt   = (bx >> 2) & 63;
    const int ks   = bx & 3;
    const int q0   = qt << 6;
    const int tid  = threadIdx.x;
    const int wave = tid >> 6;
    const int lane = tid & 63;
    const int l15  = lane & 15;
    const int quad = lane >> 4;

    const f32x4 zf = {0.f, 0.f, 0.f, 0.f};
    const hv8 qf = *reinterpret_cast<const hv8*>(
        bqT + ((size_t)n*NHW + q0 + wave*16 + l15)*CQK + quad*8);

    float mx = -1e30f;

    for (int kt = ks*16; kt < ks*16 + 16; ++kt) {
        const int k0 = kt << 6;
        #pragma unroll
        for (int f = 0; f < 4; ++f) {
            hv8 kf = *reinterpret_cast<const hv8*>(
                ckT + ((size_t)n*NHW + k0 + f*16 + l15)*CQK + quad*8);
            f32x4 s = __builtin_amdgcn_mfma_f32_16x16x32_f16(kf, qf, zf, 0, 0, 0);
            mx = fmaxf(mx, fmaxf(fmaxf(s[0], s[1]), fmaxf(s[2], s[3])));
        }
    }
    mx = fmaxf(mx, __shfl_xor(mx, 16, 64));
    mx = fmaxf(mx, __shfl_xor(mx, 32, 64));
    if (lane < 16)
        atomicMax(&m_enc[n*NHW + q0 + wave*16 + l15], enc_f32(mx));
}

// ---------------------------------------------------------------------------
// Pass B v4: flash attention, fixed row max.  cg=2 AND 32 q/wave:
//  * exp/softmax-MFMA/p_lds work = round-1 level x0.5 vs round-3 (cg=2 ->
//    each (q,k) exp computed twice total, not 4x).
//  * V-read-per-PV-MFMA halved (each V ds_read_b128 feeds 2 MFMAs) -> V LDS
//    traffic halved vs round-1.
//  * Block = 4 waves x 32 q = 128 q, 128 co. Grid = 4n*32qt*2cg = 256,
//    XCD-swizzled so each XCD owns one (n,cg) -> its 1 MB dv slice is
//    L2-local. 1 block/CU, 4 waves (1/SIMD) -- relies on in-wave ILP
//    (PV(kt) independent of softmax(kt+1); V prefetched to registers).
//  * LDS 55.3 KB: V 128x64 dbuf (36.9) + p_lds (18.4).
// ---------------------------------------------------------------------------
__global__ __launch_bounds__(256) void attn_kernel(
    const _Float16* __restrict__ bqT, const _Float16* __restrict__ ckT,
    const _Float16* __restrict__ dv, const unsigned* __restrict__ m_enc,
    const float* __restrict__ a, const float* __restrict__ alpha_p,
    float* __restrict__ out)
{
    __shared__ __align__(16) _Float16 vlds[2][128 * 72];    // V tiles, 36.9 KB
    __shared__ __align__(16) _Float16 p_lds[4][2][16 * 72]; // per-wave/grp P, 18.4 KB

    // XCD swizzle: 256 blocks, 8 XCDs -> XCD k owns logical [k*32,(k+1)*32)
    const int bx   = ((blockIdx.x & 7) << 5) | (blockIdx.x >> 3);
    const int n    = bx >> 6;
    const int cg   = (bx >> 5) & 1;
    const int qt   = bx & 31;
    const int q0b  = qt << 7;           // block covers 128 q
    const int co0  = cg << 7;           // 128 output channels
    const int tid  = threadIdx.x;
    const int wave = tid >> 6;
    const int lane = tid & 63;
    const int l15  = lane & 15;
    const int quad = lane >> 4;

    const f32x4 zf = {0.f, 0.f, 0.f, 0.f};
    const _Float16 one_h = (_Float16)1.0f;
    const hv8 ones = { one_h, one_h, one_h, one_h, one_h, one_h, one_h, one_h };

    const int qA = q0b + wave*32 + l15;
    const int qB = qA + 16;
    const hv8 qfA = *reinterpret_cast<const hv8*>(
        bqT + ((size_t)n*NHW + qA)*CQK + quad*8);
    const hv8 qfB = *reinterpret_cast<const hv8*>(
        bqT + ((size_t)n*NHW + qB)*CQK + quad*8);

    const float mnegA = -dec_f32(m_enc[n*NHW + qA]);
    const float mnegB = -dec_f32(m_enc[n*NHW + qB]);
    const f32x4 minitA = {mnegA, mnegA, mnegA, mnegA};
    const f32x4 minitB = {mnegB, mnegB, mnegB, mnegB};

    f32x4 accA[8], accB[8];
    #pragma unroll
    for (int t = 0; t < 8; ++t) { accA[t] = zf; accB[t] = zf; }
    f32x4 accLA = zf, accLB = zf;

    // staging map: 256 threads, 4 x int4 each -> 128co x 64k tile
    const int co_s = tid >> 3;          // 0..31
    const int c8_s = (tid & 7) << 3;    // 0..56
    const _Float16* dvs0 = dv + ((size_t)(n*CCH + co0 + co_s))*NHW + c8_s;
    const _Float16* dvs1 = dvs0 + (size_t)32 * NHW;
    const _Float16* dvs2 = dvs0 + (size_t)64 * NHW;
    const _Float16* dvs3 = dvs0 + (size_t)96 * NHW;

    // kf base for this lane
    const _Float16* ckbase = ckT + ((size_t)n*NHW + l15)*CQK + quad*8;

    // S^T/exp for one 16-q group of a key tile -> p_lds[wave][grp]
    auto softmax_tile = [&](int grp, const hv8* kf, hv8 qf, f32x4 minit) {
        #pragma unroll
        for (int f = 0; f < 4; ++f) {
            f32x4 s = __builtin_amdgcn_mfma_f32_16x16x32_f16(kf[f], qf, minit, 0, 0, 0);
            float p0 = __builtin_amdgcn_exp2f(s[0]);
            float p1 = __builtin_amdgcn_exp2f(s[1]);
            float p2 = __builtin_amdgcn_exp2f(s[2]);
            float p3 = __builtin_amdgcn_exp2f(s[3]);
            fv2 lo = __builtin_amdgcn_cvt_pkrtz(p0, p1);
            fv2 hi = __builtin_amdgcn_cvt_pkrtz(p2, p3);
            uint2 w;
            w.x = __builtin_bit_cast(unsigned, lo);
            w.y = __builtin_bit_cast(unsigned, hi);
            *reinterpret_cast<uint2*>(
                &p_lds[wave][grp][l15*72 + f*16 + quad*4]) = w;
        }
    };

    // ---- prologue: stage V tile 0, softmax tile 0 (both groups)
    {
        int4 r0 = *reinterpret_cast<const int4*>(dvs0);
        int4 r1 = *reinterpret_cast<const int4*>(dvs1);
        int4 r2 = *reinterpret_cast<const int4*>(dvs2);
        int4 r3 = *reinterpret_cast<const int4*>(dvs3);
        *reinterpret_cast<int4*>(&vlds[0][co_s*72 + c8_s])        = r0;
        *reinterpret_cast<int4*>(&vlds[0][(co_s + 32)*72 + c8_s]) = r1;
        *reinterpret_cast<int4*>(&vlds[0][(co_s + 64)*72 + c8_s]) = r2;
        *reinterpret_cast<int4*>(&vlds[0][(co_s + 96)*72 + c8_s]) = r3;
        hv8 kf0[4];
        #pragma unroll
        for (int f = 0; f < 4; ++f)
            kf0[f] = *reinterpret_cast<const hv8*>(ckbase + (size_t)(f*16)*CQK);
        softmax_tile(0, kf0, qfA, minitA);
        softmax_tile(1, kf0, qfB, minitB);
    }
    __syncthreads();

    for (int kt = 0; kt < 64; ++kt) {
        const int k0n = (kt + 1) << 6;
        const int cur = kt & 1;

        // ---- prefetch next tile: kf fragments + V rows (registers)
        hv8 kfn[4];
        int4 nr0, nr1, nr2, nr3;
        if (kt < 63) {
            #pragma unroll
            for (int f = 0; f < 4; ++f)
                kfn[f] = *reinterpret_cast<const hv8*>(
                    ckbase + (size_t)(k0n + f*16)*CQK);
            nr0 = *reinterpret_cast<const int4*>(dvs0 + k0n);
            nr1 = *reinterpret_cast<const int4*>(dvs1 + k0n);
            nr2 = *reinterpret_cast<const int4*>(dvs2 + k0n);
            nr3 = *reinterpret_cast<const int4*>(dvs3 + k0n);
        }

        // ---- PV(kt): P fragments from p_lds (written last iter, same wave);
        //      each V fragment read feeds both q-groups.
        hv8 pfA0 = *reinterpret_cast<const hv8*>(&p_lds[wave][0][l15*72 + quad*8]);
        hv8 pfA1 = *reinterpret_cast<const hv8*>(&p_lds[wave][0][l15*72 + 32 + quad*8]);
        hv8 pfB0 = *reinterpret_cast<const hv8*>(&p_lds[wave][1][l15*72 + quad*8]);
        hv8 pfB1 = *reinterpret_cast<const hv8*>(&p_lds[wave][1][l15*72 + 32 + quad*8]);
        #pragma unroll
        for (int t = 0; t < 8; ++t) {
            hv8 d0 = *reinterpret_cast<const hv8*>(&vlds[cur][(t*16 + l15)*72 + quad*8]);
            accA[t] = __builtin_amdgcn_mfma_f32_16x16x32_f16(pfA0, d0, accA[t], 0, 0, 0);
            accB[t] = __builtin_amdgcn_mfma_f32_16x16x32_f16(pfB0, d0, accB[t], 0, 0, 0);
            hv8 d1 = *reinterpret_cast<const hv8*>(&vlds[cur][(t*16 + l15)*72 + 32 + quad*8]);
            accA[t] = __builtin_amdgcn_mfma_f32_16x16x32_f16(pfA1, d1, accA[t], 0, 0, 0);
            accB[t] = __builtin_amdgcn_mfma_f32_16x16x32_f16(pfB1, d1, accB[t], 0, 0, 0);
        }
        accLA = __builtin_amdgcn_mfma_f32_16x16x32_f16(pfA0, ones, accLA, 0, 0, 0);
        accLA = __builtin_amdgcn_mfma_f32_16x16x32_f16(pfA1, ones, accLA, 0, 0, 0);
        accLB = __builtin_amdgcn_mfma_f32_16x16x32_f16(pfB0, ones, accLB, 0, 0, 0);
        accLB = __builtin_amdgcn_mfma_f32_16x16x32_f16(pfB1, ones, accLB, 0, 0, 0);

        // ---- softmax(kt+1) into p_lds (after the pf reads above), stage V
        if (kt < 63) {
            softmax_tile(0, kfn, qfA, minitA);
            softmax_tile(1, kfn, qfB, minitB);
            *reinterpret_cast<int4*>(&vlds[cur ^ 1][co_s*72 + c8_s])        = nr0;
            *reinterpret_cast<int4*>(&vlds[cur ^ 1][(co_s + 32)*72 + c8_s]) = nr1;
            *reinterpret_cast<int4*>(&vlds[cur ^ 1][(co_s + 64)*72 + c8_s]) = nr2;
            *reinterpret_cast<int4*>(&vlds[cur ^ 1][(co_s + 96)*72 + c8_s]) = nr3;
            __syncthreads();
        }
    }

    // ---- epilogue: out[co][q..q+3] = alpha*O/l + a, float4 per lane, 2 groups
    const float alpha = alpha_p[0];
    f32x4 rlA, rlB;
    #pragma unroll
    for (int r = 0; r < 4; ++r) {
        rlA[r] = alpha / accLA[r];
        rlB[r] = alpha / accLB[r];
    }

    const int qvA = q0b + wave*32 + quad*4;
    #pragma unroll
    for (int t = 0; t < 8; ++t) {
        const int co = co0 + t*16 + l15;
        {
            const size_t off = ((size_t)n*CCH + co)*NHW + qvA;
            float4 av = *reinterpret_cast<const float4*>(a + off);
            float4 o;
            o.x = accA[t][0]*rlA[0] + av.x;
            o.y = accA[t][1]*rlA[1] + av.y;
            o.z = accA[t][2]*rlA[2] + av.z;
            o.w = accA[t][3]*rlA[3] + av.w;
            *reinterpret_cast<float4*>(out + off) = o;
        }
        {
            const size_t off = ((size_t)n*CCH + co)*NHW + qvA + 16;
            float4 av = *reinterpret_cast<const float4*>(a + off);
            float4 o;
            o.x = accB[t][0]*rlB[0] + av.x;
            o.y = accB[t][1]*rlB[1] + av.y;
            o.z = accB[t][2]*rlB[2] + av.z;
            o.w = accB[t][3]*rlB[3] + av.w;
            *reinterpret_cast<float4*>(out + off) = o;
        }
    }
}

extern "C" void kernel_launch(void* const* d_in, const int* in_sizes, int n_in,
                              void* d_out, int out_size, void* d_ws, size_t ws_size,
                              hipStream_t stream)
{
    const float* a    = (const float*)d_in[0];
    const float* b_w  = (const float*)d_in[1];
    const float* b_b  = (const float*)d_in[2];
    const float* c_w  = (const float*)d_in[3];
    const float* c_b  = (const float*)d_in[4];
    const float* d_w  = (const float*)d_in[5];
    const float* d_b  = (const float*)d_in[6];
    const float* alp  = (const float*)d_in[7];
    float* out = (float*)d_out;

    _Float16* bqT  = (_Float16*)d_ws;                 // [4][4096][32] fp16, 1 MB
    _Float16* ckT  = bqT + (size_t)4*NHW*CQK;         // [4][4096][32] fp16, 1 MB
    _Float16* dv   = ckT + (size_t)4*NHW*CQK;         // [4][256][4096] fp16, 8 MB
    unsigned* m_enc = (unsigned*)(dv + (size_t)4*CCH*NHW);  // [4][4096] u32, 64 KB
    _Float16* Wh   = (_Float16*)(m_enc + 4*NHW);      // [320][256] fp16, 160 KB

    prep_kernel<<<144, 256, 0, stream>>>(b_w, c_w, d_w, Wh, m_enc);
    proj_kernel<<<512, 256, 0, stream>>>(a, Wh, b_b, c_b, d_b, bqT, ckT, dv);
    rowmax_kernel<<<1024, 256, 0, stream>>>(bqT, ckT, m_enc);
    attn_kernel<<<256, 256, 0, stream>>>(bqT, ckT, dv, m_enc, a, alp, out);
}

// Round 5
// 176.437 us; speedup vs baseline: 1.1533x; 1.1533x over previous
//
#include <hip/hip_runtime.h>
#include <hip/hip_bf16.h>

#define CCH 256
#define CQK 32
#define NHW 4096

typedef float f32x4 __attribute__((ext_vector_type(4)));
typedef _Float16 hv8 __attribute__((ext_vector_type(8)));
typedef _Float16 hv4 __attribute__((ext_vector_type(4)));
typedef __fp16 fv2 __attribute__((ext_vector_type(2)));   // cvt_pkrtz native type

// Monotone float<->uint encoding so float max == uint max (handles negatives).
__device__ __forceinline__ unsigned enc_f32(float f) {
    unsigned u = __float_as_uint(f);
    return (u & 0x80000000u) ? ~u : (u | 0x80000000u);
}
__device__ __forceinline__ float dec_f32(unsigned u) {
    return __uint_as_float((u & 0x80000000u) ? (u ^ 0x80000000u) : ~u);
}

// ---------------------------------------------------------------------------
// Prep kernel: (a) convert Wall = concat(b_w, c_w, d_w) fp32 -> fp16 [320][256];
// b_w rows prescaled by log2(e) so QK^T comes out in exp2 units.
// (b) init m_enc = 0. Grid 144 x 256.
// ---------------------------------------------------------------------------
__global__ __launch_bounds__(256) void prep_kernel(
    const float* __restrict__ b_w, const float* __restrict__ c_w,
    const float* __restrict__ d_w, _Float16* __restrict__ Wh,
    unsigned* __restrict__ m_enc)
{
    const int bid = blockIdx.x, tid = threadIdx.x;
    if (bid < 80) {
        const int idx = (bid * 256 + tid) * 4;
        const int row = idx >> 8, col = idx & 255;
        const float* src = (row < 32) ? (b_w + row * CCH + col)
                         : (row < 64) ? (c_w + (row - 32) * CCH + col)
                                      : (d_w + (row - 64) * CCH + col);
        const float scl = (row < 32) ? 1.4426950408889634f : 1.0f;
        float4 v = *reinterpret_cast<const float4*>(src);
        _Float16* dst = Wh + (size_t)row * CCH + col;
        dst[0] = (_Float16)(v.x * scl); dst[1] = (_Float16)(v.y * scl);
        dst[2] = (_Float16)(v.z * scl); dst[3] = (_Float16)(v.w * scl);
    } else {
        m_enc[(bid - 80) * 256 + tid] = 0u;
    }
}

// ---------------------------------------------------------------------------
// Projection kernel (round-6/7 verified structure, unchanged).
// ---------------------------------------------------------------------------
__global__ __launch_bounds__(256) void proj_kernel(
    const float* __restrict__ a, const _Float16* __restrict__ Wh,
    const float* __restrict__ b_b, const float* __restrict__ c_b,
    const float* __restrict__ d_b,
    _Float16* __restrict__ bqT, _Float16* __restrict__ ckT,
    _Float16* __restrict__ dv)
{
    __shared__ _Float16 aT[32][CCH + 24];

    const int n    = blockIdx.x >> 7;
    const int i0   = (blockIdx.x & 127) << 5;
    const int tid  = threadIdx.x;
    const int lane = tid & 63;
    const int wave = tid >> 6;
    const int l15  = lane & 15;
    const int quad = lane >> 4;

    {
        const float* ap = a + (size_t)(n*CCH + tid)*NHW + i0;
        #pragma unroll
        for (int j = 0; j < 8; ++j) {
            float4 v = *reinterpret_cast<const float4*>(ap + j*4);
            aT[j*4+0][tid] = (_Float16)v.x;
            aT[j*4+1][tid] = (_Float16)v.y;
            aT[j*4+2][tid] = (_Float16)v.z;
            aT[j*4+3][tid] = (_Float16)v.w;
        }
    }
    __syncthreads();

    const f32x4 zf = {0.f, 0.f, 0.f, 0.f};
    f32x4 acc[5][2];
    #pragma unroll
    for (int t = 0; t < 5; ++t) { acc[t][0] = zf; acc[t][1] = zf; }

    const int ch0w = wave * 80;

    #pragma unroll
    for (int ks = 0; ks < 8; ++ks) {
        const int k0 = ks * 32;
        hv8 af0 = *reinterpret_cast<const hv8*>(&aT[l15][k0 + quad*8]);
        hv8 af1 = *reinterpret_cast<const hv8*>(&aT[16 + l15][k0 + quad*8]);
        #pragma unroll
        for (int t = 0; t < 5; ++t) {
            const int ch0 = ch0w + t*16;
            hv8 bf = *reinterpret_cast<const hv8*>(
                Wh + (size_t)(ch0 + l15)*CCH + k0 + quad*8);
            acc[t][0] = __builtin_amdgcn_mfma_f32_16x16x32_f16(af0, bf, acc[t][0], 0, 0, 0);
            acc[t][1] = __builtin_amdgcn_mfma_f32_16x16x32_f16(af1, bf, acc[t][1], 0, 0, 0);
        }
    }

    const int pos_b = i0 + quad*4;
    #pragma unroll
    for (int t = 0; t < 5; ++t) {
        const int ch0 = ch0w + t*16;
        if (ch0 < 64) {
            const float* bias_arr = (ch0 < 32) ? b_b : c_b;
            _Float16*    outp     = (ch0 < 32) ? bqT : ckT;
            const int    ch       = (ch0 & 31) + l15;
            const float  bias     = bias_arr[ch] *
                ((ch0 < 32) ? 1.4426950408889634f : 1.0f);
            #pragma unroll
            for (int nf = 0; nf < 2; ++nf) {
                #pragma unroll
                for (int r = 0; r < 4; ++r) {
                    const int pos = pos_b + nf*16 + r;
                    outp[((size_t)n*NHW + pos)*CQK + ch] =
                        (_Float16)(acc[t][nf][r] + bias);
                }
            }
        } else {
            const int ch   = ch0 - 64 + l15;
            const float bias = d_b[ch];
            #pragma unroll
            for (int nf = 0; nf < 2; ++nf) {
                hv4 v = { (_Float16)(acc[t][nf][0] + bias),
                          (_Float16)(acc[t][nf][1] + bias),
                          (_Float16)(acc[t][nf][2] + bias),
                          (_Float16)(acc[t][nf][3] + bias) };
                *reinterpret_cast<hv4*>(
                    dv + ((size_t)n*CCH + ch)*NHW + pos_b + nf*16) = v;
            }
        }
    }
}

// ---------------------------------------------------------------------------
// Pass A: per-q-row max of the (log2e-scaled) scores. Unchanged.
// ---------------------------------------------------------------------------
__global__ __launch_bounds__(256) void rowmax_kernel(
    const _Float16* __restrict__ bqT, const _Float16* __restrict__ ckT,
    unsigned* __restrict__ m_enc)
{
    const int bx   = blockIdx.x;
    const int n    = bx >> 8;
    const int qt   = (bx >> 2) & 63;
    const int ks   = bx & 3;
    const int q0   = qt << 6;
    const int tid  = threadIdx.x;
    const int wave = tid >> 6;
    const int lane = tid & 63;
    const int l15  = lane & 15;
    const int quad = lane >> 4;

    const f32x4 zf = {0.f, 0.f, 0.f, 0.f};
    const hv8 qf = *reinterpret_cast<const hv8*>(
        bqT + ((size_t)n*NHW + q0 + wave*16 + l15)*CQK + quad*8);

    float mx = -1e30f;

    for (int kt = ks*16; kt < ks*16 + 16; ++kt) {
        const int k0 = kt << 6;
        #pragma unroll
        for (int f = 0; f < 4; ++f) {
            hv8 kf = *reinterpret_cast<const hv8*>(
                ckT + ((size_t)n*NHW + k0 + f*16 + l15)*CQK + quad*8);
            f32x4 s = __builtin_amdgcn_mfma_f32_16x16x32_f16(kf, qf, zf, 0, 0, 0);
            mx = fmaxf(mx, fmaxf(fmaxf(s[0], s[1]), fmaxf(s[2], s[3])));
        }
    }
    mx = fmaxf(mx, __shfl_xor(mx, 16, 64));
    mx = fmaxf(mx, __shfl_xor(mx, 32, 64));
    if (lane < 16)
        atomicMax(&m_enc[n*NHW + q0 + wave*16 + l15], enc_f32(mx));
}

// ---------------------------------------------------------------------------
// Pass B v5: flash attention, fixed row max. R4's work level (cg=2, 32 q/wave
// = lowest LDS+exp traffic of any round) + IN-BLOCK KEY-SPLIT to restore
// 2 waves/SIMD (R4 was latency-bound at 1 wave/SIMD, all pipes <30%).
//  * 512-thread block = 2 k-groups x 4 waves. Group g covers keys
//    [g*2048,(g+1)*2048) with the same fixed global row-max -> partials
//    combine exactly (O=O0+O1, l=l0+l1) via a plain-LDS float merge.
//  * Block = 128 q x 128 co. Grid = 4n*32qt*2cg = 256, XCD-swizzled.
//    1 block/CU (LDS 110.6 KB) but 8 waves/CU now.
//  * Per k-group: V tile 128co x 64k double-buffered; p_lds per (wave,grp);
//    register prefetch of kf + V rows; single barrier per iter.
// ---------------------------------------------------------------------------
__global__ __launch_bounds__(512, 2) void attn_kernel(
    const _Float16* __restrict__ bqT, const _Float16* __restrict__ ckT,
    const _Float16* __restrict__ dv, const unsigned* __restrict__ m_enc,
    const float* __restrict__ a, const float* __restrict__ alpha_p,
    float* __restrict__ out)
{
    __shared__ __align__(16) _Float16 vlds[2][2][128 * 72];  // [kgrp][dbuf], 73.7 KB
    __shared__ __align__(16) _Float16 p_lds[8][2][16 * 72];  // [wave][grp], 36.9 KB

    // XCD swizzle: 256 blocks, 8 XCDs -> XCD k owns logical [k*32,(k+1)*32)
    const int bx   = ((blockIdx.x & 7) << 5) | (blockIdx.x >> 3);
    const int n    = bx >> 6;
    const int cg   = (bx >> 5) & 1;
    const int qt   = bx & 31;
    const int q0b  = qt << 7;           // block covers 128 q
    const int co0  = cg << 7;           // 128 output channels
    const int tid  = threadIdx.x;
    const int wave = tid >> 6;
    const int g    = wave >> 2;         // k-group
    const int w4   = wave & 3;          // q-subtile (32 q)
    const int lane = tid & 63;
    const int l15  = lane & 15;
    const int quad = lane >> 4;
    const int kg0  = g << 11;           // key offset of this group

    const f32x4 zf = {0.f, 0.f, 0.f, 0.f};
    const _Float16 one_h = (_Float16)1.0f;
    const hv8 ones = { one_h, one_h, one_h, one_h, one_h, one_h, one_h, one_h };

    const int qA = q0b + w4*32 + l15;
    const int qB = qA + 16;
    const hv8 qfA = *reinterpret_cast<const hv8*>(
        bqT + ((size_t)n*NHW + qA)*CQK + quad*8);
    const hv8 qfB = *reinterpret_cast<const hv8*>(
        bqT + ((size_t)n*NHW + qB)*CQK + quad*8);

    const float mnegA = -dec_f32(m_enc[n*NHW + qA]);
    const float mnegB = -dec_f32(m_enc[n*NHW + qB]);
    const f32x4 minitA = {mnegA, mnegA, mnegA, mnegA};
    const f32x4 minitB = {mnegB, mnegB, mnegB, mnegB};

    f32x4 accA[8], accB[8];
    #pragma unroll
    for (int t = 0; t < 8; ++t) { accA[t] = zf; accB[t] = zf; }
    f32x4 accLA = zf, accLB = zf;

    // staging map: 256 threads per k-group, 4 x int4 each -> 128co x 64k tile
    const int lt   = tid & 255;
    const int co_s = lt >> 3;           // 0..31
    const int c8_s = (lt & 7) << 3;     // 0..56
    const _Float16* dvs0 = dv + ((size_t)(n*CCH + co0 + co_s))*NHW + kg0 + c8_s;
    const _Float16* dvs1 = dvs0 + (size_t)32 * NHW;
    const _Float16* dvs2 = dvs0 + (size_t)64 * NHW;
    const _Float16* dvs3 = dvs0 + (size_t)96 * NHW;

    // kf base for this lane within this group's key range
    const _Float16* ckbase = ckT + ((size_t)(n*NHW + kg0 + l15))*CQK + quad*8;

    // S^T/exp for one 16-q group of a key tile -> p_lds[wave][grp]
    auto softmax_tile = [&](int grp, const hv8* kf, hv8 qf, f32x4 minit) {
        #pragma unroll
        for (int f = 0; f < 4; ++f) {
            f32x4 s = __builtin_amdgcn_mfma_f32_16x16x32_f16(kf[f], qf, minit, 0, 0, 0);
            float p0 = __builtin_amdgcn_exp2f(s[0]);
            float p1 = __builtin_amdgcn_exp2f(s[1]);
            float p2 = __builtin_amdgcn_exp2f(s[2]);
            float p3 = __builtin_amdgcn_exp2f(s[3]);
            fv2 lo = __builtin_amdgcn_cvt_pkrtz(p0, p1);
            fv2 hi = __builtin_amdgcn_cvt_pkrtz(p2, p3);
            uint2 w;
            w.x = __builtin_bit_cast(unsigned, lo);
            w.y = __builtin_bit_cast(unsigned, hi);
            *reinterpret_cast<uint2*>(
                &p_lds[wave][grp][l15*72 + f*16 + quad*4]) = w;
        }
    };

    // ---- prologue: stage V tile 0 (own group), softmax tile 0 (both q-groups)
    {
        int4 r0 = *reinterpret_cast<const int4*>(dvs0);
        int4 r1 = *reinterpret_cast<const int4*>(dvs1);
        int4 r2 = *reinterpret_cast<const int4*>(dvs2);
        int4 r3 = *reinterpret_cast<const int4*>(dvs3);
        *reinterpret_cast<int4*>(&vlds[g][0][co_s*72 + c8_s])        = r0;
        *reinterpret_cast<int4*>(&vlds[g][0][(co_s + 32)*72 + c8_s]) = r1;
        *reinterpret_cast<int4*>(&vlds[g][0][(co_s + 64)*72 + c8_s]) = r2;
        *reinterpret_cast<int4*>(&vlds[g][0][(co_s + 96)*72 + c8_s]) = r3;
        hv8 kf0[4];
        #pragma unroll
        for (int f = 0; f < 4; ++f)
            kf0[f] = *reinterpret_cast<const hv8*>(ckbase + (size_t)(f*16)*CQK);
        softmax_tile(0, kf0, qfA, minitA);
        softmax_tile(1, kf0, qfB, minitB);
    }
    __syncthreads();

    for (int kt = 0; kt < 32; ++kt) {
        const int k0n = (kt + 1) << 6;      // next tile base (within group)
        const int cur = kt & 1;

        // ---- prefetch next tile: kf fragments + V rows (registers)
        hv8 kfn[4];
        int4 nr0, nr1, nr2, nr3;
        if (kt < 31) {
            #pragma unroll
            for (int f = 0; f < 4; ++f)
                kfn[f] = *reinterpret_cast<const hv8*>(
                    ckbase + (size_t)(k0n + f*16)*CQK);
            nr0 = *reinterpret_cast<const int4*>(dvs0 + k0n);
            nr1 = *reinterpret_cast<const int4*>(dvs1 + k0n);
            nr2 = *reinterpret_cast<const int4*>(dvs2 + k0n);
            nr3 = *reinterpret_cast<const int4*>(dvs3 + k0n);
        }

        // ---- PV(kt): P fragments from p_lds (written last iter, same wave);
        //      each V fragment read feeds both q-groups.
        hv8 pfA0 = *reinterpret_cast<const hv8*>(&p_lds[wave][0][l15*72 + quad*8]);
        hv8 pfA1 = *reinterpret_cast<const hv8*>(&p_lds[wave][0][l15*72 + 32 + quad*8]);
        hv8 pfB0 = *reinterpret_cast<const hv8*>(&p_lds[wave][1][l15*72 + quad*8]);
        hv8 pfB1 = *reinterpret_cast<const hv8*>(&p_lds[wave][1][l15*72 + 32 + quad*8]);
        #pragma unroll
        for (int t = 0; t < 8; ++t) {
            hv8 d0 = *reinterpret_cast<const hv8*>(
                &vlds[g][cur][(t*16 + l15)*72 + quad*8]);
            accA[t] = __builtin_amdgcn_mfma_f32_16x16x32_f16(pfA0, d0, accA[t], 0, 0, 0);
            accB[t] = __builtin_amdgcn_mfma_f32_16x16x32_f16(pfB0, d0, accB[t], 0, 0, 0);
            hv8 d1 = *reinterpret_cast<const hv8*>(
                &vlds[g][cur][(t*16 + l15)*72 + 32 + quad*8]);
            accA[t] = __builtin_amdgcn_mfma_f32_16x16x32_f16(pfA1, d1, accA[t], 0, 0, 0);
            accB[t] = __builtin_amdgcn_mfma_f32_16x16x32_f16(pfB1, d1, accB[t], 0, 0, 0);
        }
        accLA = __builtin_amdgcn_mfma_f32_16x16x32_f16(pfA0, ones, accLA, 0, 0, 0);
        accLA = __builtin_amdgcn_mfma_f32_16x16x32_f16(pfA1, ones, accLA, 0, 0, 0);
        accLB = __builtin_amdgcn_mfma_f32_16x16x32_f16(pfB0, ones, accLB, 0, 0, 0);
        accLB = __builtin_amdgcn_mfma_f32_16x16x32_f16(pfB1, ones, accLB, 0, 0, 0);

        // ---- softmax(kt+1) into p_lds (after the pf reads above), stage V
        if (kt < 31) {
            softmax_tile(0, kfn, qfA, minitA);
            softmax_tile(1, kfn, qfB, minitB);
            *reinterpret_cast<int4*>(&vlds[g][cur ^ 1][co_s*72 + c8_s])        = nr0;
            *reinterpret_cast<int4*>(&vlds[g][cur ^ 1][(co_s + 32)*72 + c8_s]) = nr1;
            *reinterpret_cast<int4*>(&vlds[g][cur ^ 1][(co_s + 64)*72 + c8_s]) = nr2;
            *reinterpret_cast<int4*>(&vlds[g][cur ^ 1][(co_s + 96)*72 + c8_s]) = nr3;
            __syncthreads();
        }
    }

    // ---- merge the two k-groups through LDS, then epilogue (g0 writes out)
    __syncthreads();
    float* fred = reinterpret_cast<float*>(&vlds[0][0][0]);     // [128co][132q]
    float* lred = reinterpret_cast<float*>(&p_lds[0][0][0]);    // [128] l partials
    const int qloc = w4*32 + quad*4;

    if (g == 1) {       // k-group 1 publishes partials
        #pragma unroll
        for (int t = 0; t < 8; ++t) {
            *reinterpret_cast<float4*>(&fred[(t*16 + l15)*132 + qloc]) =
                *reinterpret_cast<float4*>(&accA[t]);
            *reinterpret_cast<float4*>(&fred[(t*16 + l15)*132 + qloc + 16]) =
                *reinterpret_cast<float4*>(&accB[t]);
        }
        if (l15 == 0) {
            *reinterpret_cast<float4*>(&lred[qloc]) =
                *reinterpret_cast<float4*>(&accLA);
            *reinterpret_cast<float4*>(&lred[qloc + 16]) =
                *reinterpret_cast<float4*>(&accLB);
        }
    }
    __syncthreads();

    if (g == 0) {       // k-group 0 merges + writes out
        const float alpha = alpha_p[0];
        float4 lA = *reinterpret_cast<float4*>(&lred[qloc]);
        float4 lB = *reinterpret_cast<float4*>(&lred[qloc + 16]);
        f32x4 rlA, rlB;
        rlA[0] = alpha / (accLA[0] + lA.x);
        rlA[1] = alpha / (accLA[1] + lA.y);
        rlA[2] = alpha / (accLA[2] + lA.z);
        rlA[3] = alpha / (accLA[3] + lA.w);
        rlB[0] = alpha / (accLB[0] + lB.x);
        rlB[1] = alpha / (accLB[1] + lB.y);
        rlB[2] = alpha / (accLB[2] + lB.z);
        rlB[3] = alpha / (accLB[3] + lB.w);

        const int qvA = q0b + w4*32 + quad*4;
        #pragma unroll
        for (int t = 0; t < 8; ++t) {
            const int co = co0 + t*16 + l15;
            {
                float4 po = *reinterpret_cast<float4*>(&fred[(t*16 + l15)*132 + qloc]);
                const size_t off = ((size_t)n*CCH + co)*NHW + qvA;
                float4 av = *reinterpret_cast<const float4*>(a + off);
                float4 o;
                o.x = (accA[t][0] + po.x)*rlA[0] + av.x;
                o.y = (accA[t][1] + po.y)*rlA[1] + av.y;
                o.z = (accA[t][2] + po.z)*rlA[2] + av.z;
                o.w = (accA[t][3] + po.w)*rlA[3] + av.w;
                *reinterpret_cast<float4*>(out + off) = o;
            }
            {
                float4 po = *reinterpret_cast<float4*>(&fred[(t*16 + l15)*132 + qloc + 16]);
                const size_t off = ((size_t)n*CCH + co)*NHW + qvA + 16;
                float4 av = *reinterpret_cast<const float4*>(a + off);
                float4 o;
                o.x = (accB[t][0] + po.x)*rlB[0] + av.x;
                o.y = (accB[t][1] + po.y)*rlB[1] + av.y;
                o.z = (accB[t][2] + po.z)*rlB[2] + av.z;
                o.w = (accB[t][3] + po.w)*rlB[3] + av.w;
                *reinterpret_cast<float4*>(out + off) = o;
            }
        }
    }
}

extern "C" void kernel_launch(void* const* d_in, const int* in_sizes, int n_in,
                              void* d_out, int out_size, void* d_ws, size_t ws_size,
                              hipStream_t stream)
{
    const float* a    = (const float*)d_in[0];
    const float* b_w  = (const float*)d_in[1];
    const float* b_b  = (const float*)d_in[2];
    const float* c_w  = (const float*)d_in[3];
    const float* c_b  = (const float*)d_in[4];
    const float* d_w  = (const float*)d_in[5];
    const float* d_b  = (const float*)d_in[6];
    const float* alp  = (const float*)d_in[7];
    float* out = (float*)d_out;

    _Float16* bqT  = (_Float16*)d_ws;                 // [4][4096][32] fp16, 1 MB
    _Float16* ckT  = bqT + (size_t)4*NHW*CQK;         // [4][4096][32] fp16, 1 MB
    _Float16* dv   = ckT + (size_t)4*NHW*CQK;         // [4][256][4096] fp16, 8 MB
    unsigned* m_enc = (unsigned*)(dv + (size_t)4*CCH*NHW);  // [4][4096] u32, 64 KB
    _Float16* Wh   = (_Float16*)(m_enc + 4*NHW);      // [320][256] fp16, 160 KB

    prep_kernel<<<144, 256, 0, stream>>>(b_w, c_w, d_w, Wh, m_enc);
    proj_kernel<<<512, 256, 0, stream>>>(a, Wh, b_b, c_b, d_b, bqT, ckT, dv);
    rowmax_kernel<<<1024, 256, 0, stream>>>(bqT, ckT, m_enc);
    attn_kernel<<<256, 512, 0, stream>>>(bqT, ckT, dv, m_enc, a, alp, out);
}

// Round 6
// 175.686 us; speedup vs baseline: 1.1582x; 1.0043x over previous
//
#include <hip/hip_runtime.h>
#include <hip/hip_bf16.h>

#define CCH 256
#define CQK 32
#define NHW 4096

typedef float f32x4 __attribute__((ext_vector_type(4)));
typedef _Float16 hv8 __attribute__((ext_vector_type(8)));
typedef _Float16 hv4 __attribute__((ext_vector_type(4)));
typedef __fp16 fv2 __attribute__((ext_vector_type(2)));   // cvt_pkrtz native type

// Monotone float<->uint encoding so float max == uint max (handles negatives).
__device__ __forceinline__ unsigned enc_f32(float f) {
    unsigned u = __float_as_uint(f);
    return (u & 0x80000000u) ? ~u : (u | 0x80000000u);
}
__device__ __forceinline__ float dec_f32(unsigned u) {
    return __uint_as_float((u & 0x80000000u) ? (u ^ 0x80000000u) : ~u);
}

// Direct global->LDS DMA, 16 B/lane. LDS dest = wave-uniform base + lane*16.
typedef __attribute__((address_space(3))) unsigned int lds_u32_t;
typedef __attribute__((address_space(1))) const unsigned int glb_u32_t;
__device__ __forceinline__ void gll16(const _Float16* gp, _Float16* lp) {
    __builtin_amdgcn_global_load_lds((glb_u32_t*)gp, (lds_u32_t*)lp, 16, 0, 0);
}

// ---------------------------------------------------------------------------
// Prep kernel: (a) convert Wall = concat(b_w, c_w, d_w) fp32 -> fp16 [320][256];
// b_w rows prescaled by log2(e) so QK^T comes out in exp2 units.
// (b) init m_enc = 0. Grid 144 x 256.
// ---------------------------------------------------------------------------
__global__ __launch_bounds__(256) void prep_kernel(
    const float* __restrict__ b_w, const float* __restrict__ c_w,
    const float* __restrict__ d_w, _Float16* __restrict__ Wh,
    unsigned* __restrict__ m_enc)
{
    const int bid = blockIdx.x, tid = threadIdx.x;
    if (bid < 80) {
        const int idx = (bid * 256 + tid) * 4;
        const int row = idx >> 8, col = idx & 255;
        const float* src = (row < 32) ? (b_w + row * CCH + col)
                         : (row < 64) ? (c_w + (row - 32) * CCH + col)
                                      : (d_w + (row - 64) * CCH + col);
        const float scl = (row < 32) ? 1.4426950408889634f : 1.0f;
        float4 v = *reinterpret_cast<const float4*>(src);
        _Float16* dst = Wh + (size_t)row * CCH + col;
        dst[0] = (_Float16)(v.x * scl); dst[1] = (_Float16)(v.y * scl);
        dst[2] = (_Float16)(v.z * scl); dst[3] = (_Float16)(v.w * scl);
    } else {
        m_enc[(bid - 80) * 256 + tid] = 0u;
    }
}

// ---------------------------------------------------------------------------
// Projection kernel (round-6/7 verified structure, unchanged).
// ---------------------------------------------------------------------------
__global__ __launch_bounds__(256) void proj_kernel(
    const float* __restrict__ a, const _Float16* __restrict__ Wh,
    const float* __restrict__ b_b, const float* __restrict__ c_b,
    const float* __restrict__ d_b,
    _Float16* __restrict__ bqT, _Float16* __restrict__ ckT,
    _Float16* __restrict__ dv)
{
    __shared__ _Float16 aT[32][CCH + 24];

    const int n    = blockIdx.x >> 7;
    const int i0   = (blockIdx.x & 127) << 5;
    const int tid  = threadIdx.x;
    const int lane = tid & 63;
    const int wave = tid >> 6;
    const int l15  = lane & 15;
    const int quad = lane >> 4;

    {
        const float* ap = a + (size_t)(n*CCH + tid)*NHW + i0;
        #pragma unroll
        for (int j = 0; j < 8; ++j) {
            float4 v = *reinterpret_cast<const float4*>(ap + j*4);
            aT[j*4+0][tid] = (_Float16)v.x;
            aT[j*4+1][tid] = (_Float16)v.y;
            aT[j*4+2][tid] = (_Float16)v.z;
            aT[j*4+3][tid] = (_Float16)v.w;
        }
    }
    __syncthreads();

    const f32x4 zf = {0.f, 0.f, 0.f, 0.f};
    f32x4 acc[5][2];
    #pragma unroll
    for (int t = 0; t < 5; ++t) { acc[t][0] = zf; acc[t][1] = zf; }

    const int ch0w = wave * 80;

    #pragma unroll
    for (int ks = 0; ks < 8; ++ks) {
        const int k0 = ks * 32;
        hv8 af0 = *reinterpret_cast<const hv8*>(&aT[l15][k0 + quad*8]);
        hv8 af1 = *reinterpret_cast<const hv8*>(&aT[16 + l15][k0 + quad*8]);
        #pragma unroll
        for (int t = 0; t < 5; ++t) {
            const int ch0 = ch0w + t*16;
            hv8 bf = *reinterpret_cast<const hv8*>(
                Wh + (size_t)(ch0 + l15)*CCH + k0 + quad*8);
            acc[t][0] = __builtin_amdgcn_mfma_f32_16x16x32_f16(af0, bf, acc[t][0], 0, 0, 0);
            acc[t][1] = __builtin_amdgcn_mfma_f32_16x16x32_f16(af1, bf, acc[t][1], 0, 0, 0);
        }
    }

    const int pos_b = i0 + quad*4;
    #pragma unroll
    for (int t = 0; t < 5; ++t) {
        const int ch0 = ch0w + t*16;
        if (ch0 < 64) {
            const float* bias_arr = (ch0 < 32) ? b_b : c_b;
            _Float16*    outp     = (ch0 < 32) ? bqT : ckT;
            const int    ch       = (ch0 & 31) + l15;
            const float  bias     = bias_arr[ch] *
                ((ch0 < 32) ? 1.4426950408889634f : 1.0f);
            #pragma unroll
            for (int nf = 0; nf < 2; ++nf) {
                #pragma unroll
                for (int r = 0; r < 4; ++r) {
                    const int pos = pos_b + nf*16 + r;
                    outp[((size_t)n*NHW + pos)*CQK + ch] =
                        (_Float16)(acc[t][nf][r] + bias);
                }
            }
        } else {
            const int ch   = ch0 - 64 + l15;
            const float bias = d_b[ch];
            #pragma unroll
            for (int nf = 0; nf < 2; ++nf) {
                hv4 v = { (_Float16)(acc[t][nf][0] + bias),
                          (_Float16)(acc[t][nf][1] + bias),
                          (_Float16)(acc[t][nf][2] + bias),
                          (_Float16)(acc[t][nf][3] + bias) };
                *reinterpret_cast<hv4*>(
                    dv + ((size_t)n*CCH + ch)*NHW + pos_b + nf*16) = v;
            }
        }
    }
}

// ---------------------------------------------------------------------------
// Pass A: per-q-row max of the (log2e-scaled) scores. Unchanged.
// ---------------------------------------------------------------------------
__global__ __launch_bounds__(256) void rowmax_kernel(
    const _Float16* __restrict__ bqT, const _Float16* __restrict__ ckT,
    unsigned* __restrict__ m_enc)
{
    const int bx   = blockIdx.x;
    const int n    = bx >> 8;
    const int qt   = (bx >> 2) & 63;
    const int ks   = bx & 3;
    const int q0   = qt << 6;
    const int tid  = threadIdx.x;
    const int wave = tid >> 6;
    const int lane = tid & 63;
    const int l15  = lane & 15;
    const int quad = lane >> 4;

    const f32x4 zf = {0.f, 0.f, 0.f, 0.f};
    const hv8 qf = *reinterpret_cast<const hv8*>(
        bqT + ((size_t)n*NHW + q0 + wave*16 + l15)*CQK + quad*8);

    float mx = -1e30f;

    for (int kt = ks*16; kt < ks*16 + 16; ++kt) {
        const int k0 = kt << 6;
        #pragma unroll
        for (int f = 0; f < 4; ++f) {
            hv8 kf = *reinterpret_cast<const hv8*>(
                ckT + ((size_t)n*NHW + k0 + f*16 + l15)*CQK + quad*8);
            f32x4 s = __builtin_amdgcn_mfma_f32_16x16x32_f16(kf, qf, zf, 0, 0, 0);
            mx = fmaxf(mx, fmaxf(fmaxf(s[0], s[1]), fmaxf(s[2], s[3])));
        }
    }
    mx = fmaxf(mx, __shfl_xor(mx, 16, 64));
    mx = fmaxf(mx, __shfl_xor(mx, 32, 64));
    if (lane < 16)
        atomicMax(&m_enc[n*NHW + q0 + wave*16 + l15], enc_f32(mx));
}

// ---------------------------------------------------------------------------
// Pass B v6: flash attention, fixed row max. q/wave = 64 (4 x 16-q groups):
// each V ds_read_b128 feeds 4 PV MFMAs (V LDS reads halved vs R5 -- the
// dominant pipe at ~64% busy). To keep 8 waves/CU at grid 256: k-split 4
// (4 groups x 2 waves, 1024 keys each, 16 iters). V tiles single-buffered
// (LDS budget), staged DIRECTLY by global_load_lds with the both-sides XOR
// swizzle (linear LDS dest; source pre-permuted k = 8*((i&7)^(i>>3));
// read col byte ^= (row&7)<<4) -- no staging regs, no staging ds_writes.
// P transpose via p_lds (proven path). 4-way O/l merge through LDS.
// smem carve (141312 B): vbuf 4x16384 | p 8x4x2304 | lbuf 2048.
// ---------------------------------------------------------------------------
__global__ __launch_bounds__(512, 2) void attn_kernel(
    const _Float16* __restrict__ bqT, const _Float16* __restrict__ ckT,
    const _Float16* __restrict__ dv, const unsigned* __restrict__ m_enc,
    const float* __restrict__ a, const float* __restrict__ alpha_p,
    float* __restrict__ out)
{
    __shared__ __align__(16) char smem[141312];

    // XCD swizzle: 256 blocks, 8 XCDs -> XCD k owns logical [k*32,(k+1)*32)
    const int bx   = ((blockIdx.x & 7) << 5) | (blockIdx.x >> 3);
    const int n    = bx >> 6;
    const int cg   = (bx >> 5) & 1;
    const int qt   = bx & 31;
    const int q0b  = qt << 7;           // block covers 128 q
    const int co0  = cg << 7;           // 128 output channels
    const int tid  = threadIdx.x;
    const int wave = tid >> 6;
    const int g    = wave >> 1;         // k-group 0..3, keys [g*1024,(g+1)*1024)
    const int qw   = wave & 1;          // q-half (64 q) within block
    const int lane = tid & 63;
    const int l15  = lane & 15;
    const int quad = lane >> 4;
    const int kg0  = g << 10;

    _Float16* vbuf = (_Float16*)(smem + (g << 14));          // [128 co][64 k], swizzled
    _Float16* pb   = (_Float16*)(smem + 65536 + wave*9216);  // 4 slabs of [16][72]
    float*    lbuf = (float*)(smem + 139264);                // [4 g][128 q]

    const f32x4 zf = {0.f, 0.f, 0.f, 0.f};
    const _Float16 one_h = (_Float16)1.0f;
    const hv8 ones = { one_h, one_h, one_h, one_h, one_h, one_h, one_h, one_h };

    // q fragments + fixed row max (log2 units), 4 groups of 16 q
    hv8 qf[4]; float mneg[4];
    #pragma unroll
    for (int X = 0; X < 4; ++X) {
        const int q = q0b + qw*64 + X*16 + l15;
        qf[X] = *reinterpret_cast<const hv8*>(
            bqT + ((size_t)n*NHW + q)*CQK + quad*8);
        mneg[X] = -dec_f32(m_enc[n*NHW + q]);
    }

    f32x4 acc[4][8];
    #pragma unroll
    for (int X = 0; X < 4; ++X)
        #pragma unroll
        for (int t = 0; t < 8; ++t) acc[X][t] = zf;
    f32x4 accL[4];
    #pragma unroll
    for (int X = 0; X < 4; ++X) accL[X] = zf;

    // ---- staging: 8 x global_load_lds per wave covers 64 co rows x 64 k.
    // lane i of instr j -> lds row qw*64+j*8+(i>>3), col bytes (i&7)*16 (linear);
    // source pre-permuted so swizzled READ yields original column.
    const int rl8 = lane >> 3;
    const _Float16* dvs = dv
        + (size_t)(n*CCH + co0 + qw*64 + rl8)*NHW + kg0 + 8*((lane & 7) ^ rl8);
    _Float16* ldsb = (_Float16*)(smem + (g << 14) + qw*8192);

    // kf base for this lane within this group's key range
    const _Float16* ckbase = ckT + ((size_t)(n*NHW + kg0 + l15))*CQK + quad*8;

    // swizzled V read offsets (halves)
    const int c0h = ((quad*16) ^ ((l15 & 7) << 4)) >> 1;
    const int c1h = ((64 + quad*16) ^ ((l15 & 7) << 4)) >> 1;

    // S^T/exp for one key tile, all 4 q-groups -> pb
    auto softmax_tile = [&](const hv8* kf) {
        #pragma unroll
        for (int X = 0; X < 4; ++X) {
            const f32x4 minit = {mneg[X], mneg[X], mneg[X], mneg[X]};
            #pragma unroll
            for (int f = 0; f < 4; ++f) {
                f32x4 s = __builtin_amdgcn_mfma_f32_16x16x32_f16(
                    kf[f], qf[X], minit, 0, 0, 0);
                float p0 = __builtin_amdgcn_exp2f(s[0]);
                float p1 = __builtin_amdgcn_exp2f(s[1]);
                float p2 = __builtin_amdgcn_exp2f(s[2]);
                float p3 = __builtin_amdgcn_exp2f(s[3]);
                fv2 lo = __builtin_amdgcn_cvt_pkrtz(p0, p1);
                fv2 hi = __builtin_amdgcn_cvt_pkrtz(p2, p3);
                uint2 w;
                w.x = __builtin_bit_cast(unsigned, lo);
                w.y = __builtin_bit_cast(unsigned, hi);
                *reinterpret_cast<uint2*>(
                    pb + X*1152 + l15*72 + f*16 + quad*4) = w;
            }
        }
    };

    hv8 pf0[4], pf1[4];
    auto read_pf = [&]() {
        #pragma unroll
        for (int X = 0; X < 4; ++X) {
            pf0[X] = *reinterpret_cast<const hv8*>(pb + X*1152 + l15*72 + quad*8);
            pf1[X] = *reinterpret_cast<const hv8*>(pb + X*1152 + l15*72 + 32 + quad*8);
        }
    };

    auto stage = [&](int kt) {
        #pragma unroll
        for (int j = 0; j < 8; ++j)
            gll16(dvs + (size_t)(j*8)*NHW + kt*64, ldsb + (size_t)(j*8)*64);
    };

    auto load_kf = [&](int key0, hv8* kf) {
        #pragma unroll
        for (int f = 0; f < 4; ++f)
            kf[f] = *reinterpret_cast<const hv8*>(
                ckbase + (size_t)(key0 + f*16)*CQK);
    };

    // ---- prologue: stage V(0) via DMA, softmax(0), pf(0)
    {
        stage(0);
        hv8 kf0[4];
        load_kf(0, kf0);
        softmax_tile(kf0);
        read_pf();
    }
    __syncthreads();    // drains vmcnt -> V(0) resident

    for (int kt = 0; kt < 16; ++kt) {
        hv8 kfn[4];
        if (kt < 15) load_kf((kt + 1)*64, kfn);

        // ---- PV(kt): each V fragment feeds 4 q-groups
        #pragma unroll
        for (int t = 0; t < 8; ++t) {
            const _Float16* vr = vbuf + (t*16 + l15)*64;
            hv8 d0 = *reinterpret_cast<const hv8*>(vr + c0h);
            #pragma unroll
            for (int X = 0; X < 4; ++X)
                acc[X][t] = __builtin_amdgcn_mfma_f32_16x16x32_f16(
                    pf0[X], d0, acc[X][t], 0, 0, 0);
            hv8 d1 = *reinterpret_cast<const hv8*>(vr + c1h);
            #pragma unroll
            for (int X = 0; X < 4; ++X)
                acc[X][t] = __builtin_amdgcn_mfma_f32_16x16x32_f16(
                    pf1[X], d1, acc[X][t], 0, 0, 0);
        }
        #pragma unroll
        for (int X = 0; X < 4; ++X) {
            accL[X] = __builtin_amdgcn_mfma_f32_16x16x32_f16(pf0[X], ones, accL[X], 0, 0, 0);
            accL[X] = __builtin_amdgcn_mfma_f32_16x16x32_f16(pf1[X], ones, accL[X], 0, 0, 0);
        }

        if (kt < 15) {
            softmax_tile(kfn);          // p(kt+1) -> pb (own wave region)
            __syncthreads();            // all done reading V(kt)
            stage(kt + 1);              // DMA V(kt+1) into same buffer
            read_pf();                  // pf(kt+1) from pb (same-wave order)
            __syncthreads();            // drains vmcnt -> V(kt+1) resident
        }
    }

    // ---- merge 4 k-groups through LDS, then epilogue (g0 writes out)
    __syncthreads();                    // protect smem reuse
    float* buf1 = (float*)smem;                   // [128 co][132 q]
    float* buf2 = (float*)(smem + 67584);

    if (l15 == 0) {
        #pragma unroll
        for (int X = 0; X < 4; ++X)
            *reinterpret_cast<float4*>(&lbuf[g*128 + qw*64 + X*16 + quad*4]) =
                *reinterpret_cast<float4*>(&accL[X]);
    }
    // Round A: g1 -> buf1, g3 -> buf2
    if (g == 1 || g == 3) {
        float* b = (g == 1) ? buf1 : buf2;
        #pragma unroll
        for (int X = 0; X < 4; ++X)
            #pragma unroll
            for (int t = 0; t < 8; ++t)
                *reinterpret_cast<float4*>(
                    &b[(t*16 + l15)*132 + qw*64 + X*16 + quad*4]) =
                    *reinterpret_cast<float4*>(&acc[X][t]);
    }
    __syncthreads();
    if (g == 0 || g == 2) {
        float* b = (g == 0) ? buf1 : buf2;
        #pragma unroll
        for (int X = 0; X < 4; ++X)
            #pragma unroll
            for (int t = 0; t < 8; ++t) {
                float4 p = *reinterpret_cast<float4*>(
                    &b[(t*16 + l15)*132 + qw*64 + X*16 + quad*4]);
                acc[X][t][0] += p.x; acc[X][t][1] += p.y;
                acc[X][t][2] += p.z; acc[X][t][3] += p.w;
            }
    }
    __syncthreads();
    // Round B: g2 -> buf1
    if (g == 2) {
        #pragma unroll
        for (int X = 0; X < 4; ++X)
            #pragma unroll
            for (int t = 0; t < 8; ++t)
                *reinterpret_cast<float4*>(
                    &buf1[(t*16 + l15)*132 + qw*64 + X*16 + quad*4]) =
                    *reinterpret_cast<float4*>(&acc[X][t]);
    }
    __syncthreads();
    if (g == 0) {
        const float alpha = alpha_p[0];
        #pragma unroll
        for (int X = 0; X < 4; ++X) {
            const int qloc = qw*64 + X*16 + quad*4;
            #pragma unroll
            for (int t = 0; t < 8; ++t) {
                float4 p = *reinterpret_cast<float4*>(
                    &buf1[(t*16 + l15)*132 + qloc]);
                acc[X][t][0] += p.x; acc[X][t][1] += p.y;
                acc[X][t][2] += p.z; acc[X][t][3] += p.w;
            }
            float4 l0 = *reinterpret_cast<float4*>(&lbuf[0*128 + qloc]);
            float4 l1 = *reinterpret_cast<float4*>(&lbuf[1*128 + qloc]);
            float4 l2 = *reinterpret_cast<float4*>(&lbuf[2*128 + qloc]);
            float4 l3 = *reinterpret_cast<float4*>(&lbuf[3*128 + qloc]);
            f32x4 rl;
            rl[0] = alpha / (l0.x + l1.x + l2.x + l3.x);
            rl[1] = alpha / (l0.y + l1.y + l2.y + l3.y);
            rl[2] = alpha / (l0.z + l1.z + l2.z + l3.z);
            rl[3] = alpha / (l0.w + l1.w + l2.w + l3.w);
            #pragma unroll
            for (int t = 0; t < 8; ++t) {
                const size_t off =
                    ((size_t)(n*CCH + co0 + t*16 + l15))*NHW + q0b + qloc;
                float4 av = *reinterpret_cast<const float4*>(a + off);
                float4 o;
                o.x = acc[X][t][0]*rl[0] + av.x;
                o.y = acc[X][t][1]*rl[1] + av.y;
                o.z = acc[X][t][2]*rl[2] + av.z;
                o.w = acc[X][t][3]*rl[3] + av.w;
                *reinterpret_cast<float4*>(out + off) = o;
            }
        }
    }
}

extern "C" void kernel_launch(void* const* d_in, const int* in_sizes, int n_in,
                              void* d_out, int out_size, void* d_ws, size_t ws_size,
                              hipStream_t stream)
{
    const float* a    = (const float*)d_in[0];
    const float* b_w  = (const float*)d_in[1];
    const float* b_b  = (const float*)d_in[2];
    const float* c_w  = (const float*)d_in[3];
    const float* c_b  = (const float*)d_in[4];
    const float* d_w  = (const float*)d_in[5];
    const float* d_b  = (const float*)d_in[6];
    const float* alp  = (const float*)d_in[7];
    float* out = (float*)d_out;

    _Float16* bqT  = (_Float16*)d_ws;                 // [4][4096][32] fp16, 1 MB
    _Float16* ckT  = bqT + (size_t)4*NHW*CQK;         // [4][4096][32] fp16, 1 MB
    _Float16* dv   = ckT + (size_t)4*NHW*CQK;         // [4][256][4096] fp16, 8 MB
    unsigned* m_enc = (unsigned*)(dv + (size_t)4*CCH*NHW);  // [4][4096] u32, 64 KB
    _Float16* Wh   = (_Float16*)(m_enc + 4*NHW);      // [320][256] fp16, 160 KB

    prep_kernel<<<144, 256, 0, stream>>>(b_w, c_w, d_w, Wh, m_enc);
    proj_kernel<<<512, 256, 0, stream>>>(a, Wh, b_b, c_b, d_b, bqT, ckT, dv);
    rowmax_kernel<<<1024, 256, 0, stream>>>(bqT, ckT, m_enc);
    attn_kernel<<<256, 512, 0, stream>>>(bqT, ckT, dv, m_enc, a, alp, out);
}

// Round 7
// 165.481 us; speedup vs baseline: 1.2296x; 1.0617x over previous
//
#include <hip/hip_runtime.h>
#include <hip/hip_bf16.h>

#define CCH 256
#define CQK 32
#define NHW 4096

typedef float f32x4 __attribute__((ext_vector_type(4)));
typedef _Float16 hv8 __attribute__((ext_vector_type(8)));
typedef _Float16 hv4 __attribute__((ext_vector_type(4)));
typedef __fp16 fv2 __attribute__((ext_vector_type(2)));   // cvt_pkrtz native type

// Direct global->LDS DMA, 16 B/lane. LDS dest = wave-uniform base + lane*16.
typedef __attribute__((address_space(3))) unsigned int lds_u32_t;
typedef __attribute__((address_space(1))) const unsigned int glb_u32_t;
__device__ __forceinline__ void gll16(const _Float16* gp, _Float16* lp) {
    __builtin_amdgcn_global_load_lds((glb_u32_t*)gp, (lds_u32_t*)lp, 16, 0, 0);
}

// ---------------------------------------------------------------------------
// Prep kernel: convert Wall = concat(b_w, c_w, d_w) fp32 -> fp16 [320][256];
// b_w rows prescaled by log2(e) so QK^T comes out in exp2 units. Grid 80 x 256.
// ---------------------------------------------------------------------------
__global__ __launch_bounds__(256) void prep_kernel(
    const float* __restrict__ b_w, const float* __restrict__ c_w,
    const float* __restrict__ d_w, _Float16* __restrict__ Wh)
{
    const int bid = blockIdx.x, tid = threadIdx.x;
    const int idx = (bid * 256 + tid) * 4;
    const int row = idx >> 8, col = idx & 255;
    const float* src = (row < 32) ? (b_w + row * CCH + col)
                     : (row < 64) ? (c_w + (row - 32) * CCH + col)
                                  : (d_w + (row - 64) * CCH + col);
    const float scl = (row < 32) ? 1.4426950408889634f : 1.0f;
    float4 v = *reinterpret_cast<const float4*>(src);
    _Float16* dst = Wh + (size_t)row * CCH + col;
    dst[0] = (_Float16)(v.x * scl); dst[1] = (_Float16)(v.y * scl);
    dst[2] = (_Float16)(v.z * scl); dst[3] = (_Float16)(v.w * scl);
}

// ---------------------------------------------------------------------------
// Projection kernel (verified structure, unchanged).
// ---------------------------------------------------------------------------
__global__ __launch_bounds__(256) void proj_kernel(
    const float* __restrict__ a, const _Float16* __restrict__ Wh,
    const float* __restrict__ b_b, const float* __restrict__ c_b,
    const float* __restrict__ d_b,
    _Float16* __restrict__ bqT, _Float16* __restrict__ ckT,
    _Float16* __restrict__ dv)
{
    __shared__ _Float16 aT[32][CCH + 24];

    const int n    = blockIdx.x >> 7;
    const int i0   = (blockIdx.x & 127) << 5;
    const int tid  = threadIdx.x;
    const int lane = tid & 63;
    const int wave = tid >> 6;
    const int l15  = lane & 15;
    const int quad = lane >> 4;

    {
        const float* ap = a + (size_t)(n*CCH + tid)*NHW + i0;
        #pragma unroll
        for (int j = 0; j < 8; ++j) {
            float4 v = *reinterpret_cast<const float4*>(ap + j*4);
            aT[j*4+0][tid] = (_Float16)v.x;
            aT[j*4+1][tid] = (_Float16)v.y;
            aT[j*4+2][tid] = (_Float16)v.z;
            aT[j*4+3][tid] = (_Float16)v.w;
        }
    }
    __syncthreads();

    const f32x4 zf = {0.f, 0.f, 0.f, 0.f};
    f32x4 acc[5][2];
    #pragma unroll
    for (int t = 0; t < 5; ++t) { acc[t][0] = zf; acc[t][1] = zf; }

    const int ch0w = wave * 80;

    #pragma unroll
    for (int ks = 0; ks < 8; ++ks) {
        const int k0 = ks * 32;
        hv8 af0 = *reinterpret_cast<const hv8*>(&aT[l15][k0 + quad*8]);
        hv8 af1 = *reinterpret_cast<const hv8*>(&aT[16 + l15][k0 + quad*8]);
        #pragma unroll
        for (int t = 0; t < 5; ++t) {
            const int ch0 = ch0w + t*16;
            hv8 bf = *reinterpret_cast<const hv8*>(
                Wh + (size_t)(ch0 + l15)*CCH + k0 + quad*8);
            acc[t][0] = __builtin_amdgcn_mfma_f32_16x16x32_f16(af0, bf, acc[t][0], 0, 0, 0);
            acc[t][1] = __builtin_amdgcn_mfma_f32_16x16x32_f16(af1, bf, acc[t][1], 0, 0, 0);
        }
    }

    const int pos_b = i0 + quad*4;
    #pragma unroll
    for (int t = 0; t < 5; ++t) {
        const int ch0 = ch0w + t*16;
        if (ch0 < 64) {
            const float* bias_arr = (ch0 < 32) ? b_b : c_b;
            _Float16*    outp     = (ch0 < 32) ? bqT : ckT;
            const int    ch       = (ch0 & 31) + l15;
            const float  bias     = bias_arr[ch] *
                ((ch0 < 32) ? 1.4426950408889634f : 1.0f);
            #pragma unroll
            for (int nf = 0; nf < 2; ++nf) {
                #pragma unroll
                for (int r = 0; r < 4; ++r) {
                    const int pos = pos_b + nf*16 + r;
                    outp[((size_t)n*NHW + pos)*CQK + ch] =
                        (_Float16)(acc[t][nf][r] + bias);
                }
            }
        } else {
            const int ch   = ch0 - 64 + l15;
            const float bias = d_b[ch];
            #pragma unroll
            for (int nf = 0; nf < 2; ++nf) {
                hv4 v = { (_Float16)(acc[t][nf][0] + bias),
                          (_Float16)(acc[t][nf][1] + bias),
                          (_Float16)(acc[t][nf][2] + bias),
                          (_Float16)(acc[t][nf][3] + bias) };
                *reinterpret_cast<hv4*>(
                    dv + ((size_t)n*CCH + ch)*NHW + pos_b + nf*16) = v;
            }
        }
    }
}

// ---------------------------------------------------------------------------
// Pass B v7: flash attention with FUSED ROW-MAX PROLOGUE (rowmax kernel and
// m_enc buffer removed). Each (g,qw) wave computes the max of its 1024-key
// range (reusing ckbase/qf), publishes to a 2 KB LDS slab, one barrier,
// cross-group max -> exact global row max (deterministic MFMA, identical to
// the old two-pass value). Main loop = R6 proven: q/wave=64 (4 X-groups,
// each V ds_read_b128 feeds 4 MFMAs), k-split 4, V single-buffered staged by
// global_load_lds with both-sides XOR swizzle, P via p_lds, 4-way LDS merge.
// smem carve (141312 B): vbuf 4x16384 | p 8x4x2304 | lmax/lbuf 2048.
// ---------------------------------------------------------------------------
__global__ __launch_bounds__(512, 2) void attn_kernel(
    const _Float16* __restrict__ bqT, const _Float16* __restrict__ ckT,
    const _Float16* __restrict__ dv,
    const float* __restrict__ a, const float* __restrict__ alpha_p,
    float* __restrict__ out)
{
    __shared__ __align__(16) char smem[141312];

    // XCD swizzle: 256 blocks, 8 XCDs -> XCD k owns logical [k*32,(k+1)*32)
    const int bx   = ((blockIdx.x & 7) << 5) | (blockIdx.x >> 3);
    const int n    = bx >> 6;
    const int cg   = (bx >> 5) & 1;
    const int qt   = bx & 31;
    const int q0b  = qt << 7;           // block covers 128 q
    const int co0  = cg << 7;           // 128 output channels
    const int tid  = threadIdx.x;
    const int wave = tid >> 6;
    const int g    = wave >> 1;         // k-group 0..3, keys [g*1024,(g+1)*1024)
    const int qw   = wave & 1;          // q-half (64 q) within block
    const int lane = tid & 63;
    const int l15  = lane & 15;
    const int quad = lane >> 4;
    const int kg0  = g << 10;

    _Float16* vbuf = (_Float16*)(smem + (g << 14));          // [128 co][64 k], swizzled
    _Float16* pb   = (_Float16*)(smem + 65536 + wave*9216);  // 4 slabs of [16][72]
    float*    lbuf = (float*)(smem + 139264);                // lmax, then l partials

    const f32x4 zf = {0.f, 0.f, 0.f, 0.f};
    const _Float16 one_h = (_Float16)1.0f;
    const hv8 ones = { one_h, one_h, one_h, one_h, one_h, one_h, one_h, one_h };

    // q fragments, 4 groups of 16 q
    hv8 qf[4];
    #pragma unroll
    for (int X = 0; X < 4; ++X) {
        const int q = q0b + qw*64 + X*16 + l15;
        qf[X] = *reinterpret_cast<const hv8*>(
            bqT + ((size_t)n*NHW + q)*CQK + quad*8);
    }

    // kf base for this lane within this group's key range
    const _Float16* ckbase = ckT + ((size_t)(n*NHW + kg0 + l15))*CQK + quad*8;

    // ---- fused row-max prologue: max over this k-group's 1024 keys,
    //      then cross-group max through LDS.
    float mneg[4];
    {
        float mx[4];
        #pragma unroll
        for (int X = 0; X < 4; ++X) mx[X] = -1e30f;
        for (int kt = 0; kt < 16; ++kt) {
            #pragma unroll
            for (int f = 0; f < 4; ++f) {
                hv8 kf = *reinterpret_cast<const hv8*>(
                    ckbase + (size_t)(kt*64 + f*16)*CQK);
                #pragma unroll
                for (int X = 0; X < 4; ++X) {
                    f32x4 s = __builtin_amdgcn_mfma_f32_16x16x32_f16(
                        kf, qf[X], zf, 0, 0, 0);
                    mx[X] = fmaxf(mx[X],
                        fmaxf(fmaxf(s[0], s[1]), fmaxf(s[2], s[3])));
                }
            }
        }
        #pragma unroll
        for (int X = 0; X < 4; ++X) {
            mx[X] = fmaxf(mx[X], __shfl_xor(mx[X], 16, 64));
            mx[X] = fmaxf(mx[X], __shfl_xor(mx[X], 32, 64));
        }
        if (lane < 16) {
            #pragma unroll
            for (int X = 0; X < 4; ++X)
                lbuf[(g*2 + qw)*64 + X*16 + l15] = mx[X];
        }
        __syncthreads();
        #pragma unroll
        for (int X = 0; X < 4; ++X) {
            const int qi = qw*64 + X*16 + l15;
            float m0 = lbuf[(0*2 + qw)*64 + X*16 + l15];
            float m1 = lbuf[(1*2 + qw)*64 + X*16 + l15];
            float m2 = lbuf[(2*2 + qw)*64 + X*16 + l15];
            float m3 = lbuf[(3*2 + qw)*64 + X*16 + l15];
            (void)qi;
            mneg[X] = -fmaxf(fmaxf(m0, m1), fmaxf(m2, m3));
        }
        __syncthreads();
    }

    f32x4 acc[4][8];
    #pragma unroll
    for (int X = 0; X < 4; ++X)
        #pragma unroll
        for (int t = 0; t < 8; ++t) acc[X][t] = zf;
    f32x4 accL[4];
    #pragma unroll
    for (int X = 0; X < 4; ++X) accL[X] = zf;

    // ---- staging: 8 x global_load_lds per wave covers 64 co rows x 64 k.
    // lane i of instr j -> lds row qw*64+j*8+(i>>3), col bytes (i&7)*16 (linear);
    // source pre-permuted so swizzled READ yields original column.
    const int rl8 = lane >> 3;
    const _Float16* dvs = dv
        + (size_t)(n*CCH + co0 + qw*64 + rl8)*NHW + kg0 + 8*((lane & 7) ^ rl8);
    _Float16* ldsb = (_Float16*)(smem + (g << 14) + qw*8192);

    // swizzled V read offsets (halves)
    const int c0h = ((quad*16) ^ ((l15 & 7) << 4)) >> 1;
    const int c1h = ((64 + quad*16) ^ ((l15 & 7) << 4)) >> 1;

    // S^T/exp for one key tile, all 4 q-groups -> pb
    auto softmax_tile = [&](const hv8* kf) {
        #pragma unroll
        for (int X = 0; X < 4; ++X) {
            const f32x4 minit = {mneg[X], mneg[X], mneg[X], mneg[X]};
            #pragma unroll
            for (int f = 0; f < 4; ++f) {
                f32x4 s = __builtin_amdgcn_mfma_f32_16x16x32_f16(
                    kf[f], qf[X], minit, 0, 0, 0);
                float p0 = __builtin_amdgcn_exp2f(s[0]);
                float p1 = __builtin_amdgcn_exp2f(s[1]);
                float p2 = __builtin_amdgcn_exp2f(s[2]);
                float p3 = __builtin_amdgcn_exp2f(s[3]);
                fv2 lo = __builtin_amdgcn_cvt_pkrtz(p0, p1);
                fv2 hi = __builtin_amdgcn_cvt_pkrtz(p2, p3);
                uint2 w;
                w.x = __builtin_bit_cast(unsigned, lo);
                w.y = __builtin_bit_cast(unsigned, hi);
                *reinterpret_cast<uint2*>(
                    pb + X*1152 + l15*72 + f*16 + quad*4) = w;
            }
        }
    };

    hv8 pf0[4], pf1[4];
    auto read_pf = [&]() {
        #pragma unroll
        for (int X = 0; X < 4; ++X) {
            pf0[X] = *reinterpret_cast<const hv8*>(pb + X*1152 + l15*72 + quad*8);
            pf1[X] = *reinterpret_cast<const hv8*>(pb + X*1152 + l15*72 + 32 + quad*8);
        }
    };

    auto stage = [&](int kt) {
        #pragma unroll
        for (int j = 0; j < 8; ++j)
            gll16(dvs + (size_t)(j*8)*NHW + kt*64, ldsb + (size_t)(j*8)*64);
    };

    auto load_kf = [&](int key0, hv8* kf) {
        #pragma unroll
        for (int f = 0; f < 4; ++f)
            kf[f] = *reinterpret_cast<const hv8*>(
                ckbase + (size_t)(key0 + f*16)*CQK);
    };

    // ---- prologue: stage V(0) via DMA, softmax(0), pf(0)
    {
        stage(0);
        hv8 kf0[4];
        load_kf(0, kf0);
        softmax_tile(kf0);
        read_pf();
    }
    __syncthreads();    // drains vmcnt -> V(0) resident

    for (int kt = 0; kt < 16; ++kt) {
        hv8 kfn[4];
        if (kt < 15) load_kf((kt + 1)*64, kfn);

        // ---- PV(kt): each V fragment feeds 4 q-groups
        #pragma unroll
        for (int t = 0; t < 8; ++t) {
            const _Float16* vr = vbuf + (t*16 + l15)*64;
            hv8 d0 = *reinterpret_cast<const hv8*>(vr + c0h);
            #pragma unroll
            for (int X = 0; X < 4; ++X)
                acc[X][t] = __builtin_amdgcn_mfma_f32_16x16x32_f16(
                    pf0[X], d0, acc[X][t], 0, 0, 0);
            hv8 d1 = *reinterpret_cast<const hv8*>(vr + c1h);
            #pragma unroll
            for (int X = 0; X < 4; ++X)
                acc[X][t] = __builtin_amdgcn_mfma_f32_16x16x32_f16(
                    pf1[X], d1, acc[X][t], 0, 0, 0);
        }
        #pragma unroll
        for (int X = 0; X < 4; ++X) {
            accL[X] = __builtin_amdgcn_mfma_f32_16x16x32_f16(pf0[X], ones, accL[X], 0, 0, 0);
            accL[X] = __builtin_amdgcn_mfma_f32_16x16x32_f16(pf1[X], ones, accL[X], 0, 0, 0);
        }

        if (kt < 15) {
            softmax_tile(kfn);          // p(kt+1) -> pb (own wave region)
            __syncthreads();            // all done reading V(kt)
            stage(kt + 1);              // DMA V(kt+1) into same buffer
            read_pf();                  // pf(kt+1) from pb (same-wave order)
            __syncthreads();            // drains vmcnt -> V(kt+1) resident
        }
    }

    // ---- merge 4 k-groups through LDS, then epilogue (g0 writes out)
    __syncthreads();                    // protect smem reuse
    float* buf1 = (float*)smem;                   // [128 co][132 q]
    float* buf2 = (float*)(smem + 67584);

    if (l15 == 0) {
        #pragma unroll
        for (int X = 0; X < 4; ++X)
            *reinterpret_cast<float4*>(&lbuf[g*128 + qw*64 + X*16 + quad*4]) =
                *reinterpret_cast<float4*>(&accL[X]);
    }
    // Round A: g1 -> buf1, g3 -> buf2
    if (g == 1 || g == 3) {
        float* b = (g == 1) ? buf1 : buf2;
        #pragma unroll
        for (int X = 0; X < 4; ++X)
            #pragma unroll
            for (int t = 0; t < 8; ++t)
                *reinterpret_cast<float4*>(
                    &b[(t*16 + l15)*132 + qw*64 + X*16 + quad*4]) =
                    *reinterpret_cast<float4*>(&acc[X][t]);
    }
    __syncthreads();
    if (g == 0 || g == 2) {
        float* b = (g == 0) ? buf1 : buf2;
        #pragma unroll
        for (int X = 0; X < 4; ++X)
            #pragma unroll
            for (int t = 0; t < 8; ++t) {
                float4 p = *reinterpret_cast<float4*>(
                    &b[(t*16 + l15)*132 + qw*64 + X*16 + quad*4]);
                acc[X][t][0] += p.x; acc[X][t][1] += p.y;
                acc[X][t][2] += p.z; acc[X][t][3] += p.w;
            }
    }
    __syncthreads();
    // Round B: g2 -> buf1
    if (g == 2) {
        #pragma unroll
        for (int X = 0; X < 4; ++X)
            #pragma unroll
            for (int t = 0; t < 8; ++t)
                *reinterpret_cast<float4*>(
                    &buf1[(t*16 + l15)*132 + qw*64 + X*16 + quad*4]) =
                    *reinterpret_cast<float4*>(&acc[X][t]);
    }
    __syncthreads();
    if (g == 0) {
        const float alpha = alpha_p[0];
        #pragma unroll
        for (int X = 0; X < 4; ++X) {
            const int qloc = qw*64 + X*16 + quad*4;
            #pragma unroll
            for (int t = 0; t < 8; ++t) {
                float4 p = *reinterpret_cast<float4*>(
                    &buf1[(t*16 + l15)*132 + qloc]);
                acc[X][t][0] += p.x; acc[X][t][1] += p.y;
                acc[X][t][2] += p.z; acc[X][t][3] += p.w;
            }
            float4 l0 = *reinterpret_cast<float4*>(&lbuf[0*128 + qloc]);
            float4 l1 = *reinterpret_cast<float4*>(&lbuf[1*128 + qloc]);
            float4 l2 = *reinterpret_cast<float4*>(&lbuf[2*128 + qloc]);
            float4 l3 = *reinterpret_cast<float4*>(&lbuf[3*128 + qloc]);
            f32x4 rl;
            rl[0] = alpha / (l0.x + l1.x + l2.x + l3.x);
            rl[1] = alpha / (l0.y + l1.y + l2.y + l3.y);
            rl[2] = alpha / (l0.z + l1.z + l2.z + l3.z);
            rl[3] = alpha / (l0.w + l1.w + l2.w + l3.w);
            #pragma unroll
            for (int t = 0; t < 8; ++t) {
                const size_t off =
                    ((size_t)(n*CCH + co0 + t*16 + l15))*NHW + q0b + qloc;
                float4 av = *reinterpret_cast<const float4*>(a + off);
                float4 o;
                o.x = acc[X][t][0]*rl[0] + av.x;
                o.y = acc[X][t][1]*rl[1] + av.y;
                o.z = acc[X][t][2]*rl[2] + av.z;
                o.w = acc[X][t][3]*rl[3] + av.w;
                *reinterpret_cast<float4*>(out + off) = o;
            }
        }
    }
}

extern "C" void kernel_launch(void* const* d_in, const int* in_sizes, int n_in,
                              void* d_out, int out_size, void* d_ws, size_t ws_size,
                              hipStream_t stream)
{
    const float* a    = (const float*)d_in[0];
    const float* b_w  = (const float*)d_in[1];
    const float* b_b  = (const float*)d_in[2];
    const float* c_w  = (const float*)d_in[3];
    const float* c_b  = (const float*)d_in[4];
    const float* d_w  = (const float*)d_in[5];
    const float* d_b  = (const float*)d_in[6];
    const float* alp  = (const float*)d_in[7];
    float* out = (float*)d_out;

    _Float16* bqT  = (_Float16*)d_ws;                 // [4][4096][32] fp16, 1 MB
    _Float16* ckT  = bqT + (size_t)4*NHW*CQK;         // [4][4096][32] fp16, 1 MB
    _Float16* dv   = ckT + (size_t)4*NHW*CQK;         // [4][256][4096] fp16, 8 MB
    _Float16* Wh   = dv + (size_t)4*CCH*NHW;          // [320][256] fp16, 160 KB

    prep_kernel<<<80, 256, 0, stream>>>(b_w, c_w, d_w, Wh);
    proj_kernel<<<512, 256, 0, stream>>>(a, Wh, b_b, c_b, d_b, bqT, ckT, dv);
    attn_kernel<<<256, 512, 0, stream>>>(bqT, ckT, dv, a, alp, out);
}

// Round 8
// 165.032 us; speedup vs baseline: 1.2329x; 1.0027x over previous
//
#include <hip/hip_runtime.h>
#include <hip/hip_bf16.h>

#define CCH 256
#define CQK 32
#define NHW 4096

typedef float f32x4 __attribute__((ext_vector_type(4)));
typedef _Float16 hv8 __attribute__((ext_vector_type(8)));
typedef _Float16 hv4 __attribute__((ext_vector_type(4)));
typedef __fp16 fv2 __attribute__((ext_vector_type(2)));   // cvt_pkrtz native type

// Direct global->LDS DMA, 16 B/lane. LDS dest = wave-uniform base + lane*16.
typedef __attribute__((address_space(3))) unsigned int lds_u32_t;
typedef __attribute__((address_space(1))) const unsigned int glb_u32_t;
__device__ __forceinline__ void gll16(const _Float16* gp, _Float16* lp) {
    __builtin_amdgcn_global_load_lds((glb_u32_t*)gp, (lds_u32_t*)lp, 16, 0, 0);
}

// ---------------------------------------------------------------------------
// Prep kernel: convert Wall = concat(b_w, c_w, d_w) fp32 -> fp16 [320][256];
// b_w rows prescaled by log2(e) so QK^T comes out in exp2 units. Grid 80 x 256.
// ---------------------------------------------------------------------------
__global__ __launch_bounds__(256) void prep_kernel(
    const float* __restrict__ b_w, const float* __restrict__ c_w,
    const float* __restrict__ d_w, _Float16* __restrict__ Wh)
{
    const int bid = blockIdx.x, tid = threadIdx.x;
    const int idx = (bid * 256 + tid) * 4;
    const int row = idx >> 8, col = idx & 255;
    const float* src = (row < 32) ? (b_w + row * CCH + col)
                     : (row < 64) ? (c_w + (row - 32) * CCH + col)
                                  : (d_w + (row - 64) * CCH + col);
    const float scl = (row < 32) ? 1.4426950408889634f : 1.0f;
    float4 v = *reinterpret_cast<const float4*>(src);
    _Float16* dst = Wh + (size_t)row * CCH + col;
    dst[0] = (_Float16)(v.x * scl); dst[1] = (_Float16)(v.y * scl);
    dst[2] = (_Float16)(v.z * scl); dst[3] = (_Float16)(v.w * scl);
}

// ---------------------------------------------------------------------------
// Projection kernel (verified structure, unchanged).
// ---------------------------------------------------------------------------
__global__ __launch_bounds__(256) void proj_kernel(
    const float* __restrict__ a, const _Float16* __restrict__ Wh,
    const float* __restrict__ b_b, const float* __restrict__ c_b,
    const float* __restrict__ d_b,
    _Float16* __restrict__ bqT, _Float16* __restrict__ ckT,
    _Float16* __restrict__ dv)
{
    __shared__ _Float16 aT[32][CCH + 24];

    const int n    = blockIdx.x >> 7;
    const int i0   = (blockIdx.x & 127) << 5;
    const int tid  = threadIdx.x;
    const int lane = tid & 63;
    const int wave = tid >> 6;
    const int l15  = lane & 15;
    const int quad = lane >> 4;

    {
        const float* ap = a + (size_t)(n*CCH + tid)*NHW + i0;
        #pragma unroll
        for (int j = 0; j < 8; ++j) {
            float4 v = *reinterpret_cast<const float4*>(ap + j*4);
            aT[j*4+0][tid] = (_Float16)v.x;
            aT[j*4+1][tid] = (_Float16)v.y;
            aT[j*4+2][tid] = (_Float16)v.z;
            aT[j*4+3][tid] = (_Float16)v.w;
        }
    }
    __syncthreads();

    const f32x4 zf = {0.f, 0.f, 0.f, 0.f};
    f32x4 acc[5][2];
    #pragma unroll
    for (int t = 0; t < 5; ++t) { acc[t][0] = zf; acc[t][1] = zf; }

    const int ch0w = wave * 80;

    #pragma unroll
    for (int ks = 0; ks < 8; ++ks) {
        const int k0 = ks * 32;
        hv8 af0 = *reinterpret_cast<const hv8*>(&aT[l15][k0 + quad*8]);
        hv8 af1 = *reinterpret_cast<const hv8*>(&aT[16 + l15][k0 + quad*8]);
        #pragma unroll
        for (int t = 0; t < 5; ++t) {
            const int ch0 = ch0w + t*16;
            hv8 bf = *reinterpret_cast<const hv8*>(
                Wh + (size_t)(ch0 + l15)*CCH + k0 + quad*8);
            acc[t][0] = __builtin_amdgcn_mfma_f32_16x16x32_f16(af0, bf, acc[t][0], 0, 0, 0);
            acc[t][1] = __builtin_amdgcn_mfma_f32_16x16x32_f16(af1, bf, acc[t][1], 0, 0, 0);
        }
    }

    const int pos_b = i0 + quad*4;
    #pragma unroll
    for (int t = 0; t < 5; ++t) {
        const int ch0 = ch0w + t*16;
        if (ch0 < 64) {
            const float* bias_arr = (ch0 < 32) ? b_b : c_b;
            _Float16*    outp     = (ch0 < 32) ? bqT : ckT;
            const int    ch       = (ch0 & 31) + l15;
            const float  bias     = bias_arr[ch] *
                ((ch0 < 32) ? 1.4426950408889634f : 1.0f);
            #pragma unroll
            for (int nf = 0; nf < 2; ++nf) {
                #pragma unroll
                for (int r = 0; r < 4; ++r) {
                    const int pos = pos_b + nf*16 + r;
                    outp[((size_t)n*NHW + pos)*CQK + ch] =
                        (_Float16)(acc[t][nf][r] + bias);
                }
            }
        } else {
            const int ch   = ch0 - 64 + l15;
            const float bias = d_b[ch];
            #pragma unroll
            for (int nf = 0; nf < 2; ++nf) {
                hv4 v = { (_Float16)(acc[t][nf][0] + bias),
                          (_Float16)(acc[t][nf][1] + bias),
                          (_Float16)(acc[t][nf][2] + bias),
                          (_Float16)(acc[t][nf][3] + bias) };
                *reinterpret_cast<hv4*>(
                    dv + ((size_t)n*CCH + ch)*NHW + pos_b + nf*16) = v;
            }
        }
    }
}

// ---------------------------------------------------------------------------
// Pass B v8: flash attention with ONLINE SOFTMAX + defer-max (THR=8, log2
// units; P bounded by 2^8, fp16-safe). The two-pass row max (R7's fused
// prologue, ~8.4us of L2-load latency) is gone. Per tile, per 16-q group:
// tile max = 15 fmax + 2 shfl_xor; if tm > THR, rescale acc/accL by
// exp2(-upd) (row scales gathered via __shfl from lanes quad*4+r) and fold
// upd into mneg (the MFMA C-operand). k-groups end with different m ->
// epilogue aligns partials to the common max (publish m to LDS, barrier,
// rescale) before the existing O/l merge. Main loop otherwise = R6 proven:
// q/wave=64, k-split 4, V single-buffered via global_load_lds with
// both-sides XOR swizzle, P via p_lds.
// smem carve (143360 B): vbuf 4x16384 | p 8x4x2304 | lbuf 2048 | mbuf 2048.
// ---------------------------------------------------------------------------
__global__ __launch_bounds__(512, 2) void attn_kernel(
    const _Float16* __restrict__ bqT, const _Float16* __restrict__ ckT,
    const _Float16* __restrict__ dv,
    const float* __restrict__ a, const float* __restrict__ alpha_p,
    float* __restrict__ out)
{
    __shared__ __align__(16) char smem[143360];

    // XCD swizzle: 256 blocks, 8 XCDs -> XCD k owns logical [k*32,(k+1)*32)
    const int bx   = ((blockIdx.x & 7) << 5) | (blockIdx.x >> 3);
    const int n    = bx >> 6;
    const int cg   = (bx >> 5) & 1;
    const int qt   = bx & 31;
    const int q0b  = qt << 7;           // block covers 128 q
    const int co0  = cg << 7;           // 128 output channels
    const int tid  = threadIdx.x;
    const int wave = tid >> 6;
    const int g    = wave >> 1;         // k-group 0..3, keys [g*1024,(g+1)*1024)
    const int qw   = wave & 1;          // q-half (64 q) within block
    const int lane = tid & 63;
    const int l15  = lane & 15;
    const int quad = lane >> 4;
    const int kg0  = g << 10;

    _Float16* vbuf = (_Float16*)(smem + (g << 14));          // [128 co][64 k], swizzled
    _Float16* pb   = (_Float16*)(smem + 65536 + wave*9216);  // 4 slabs of [16][72]
    float*    lbuf = (float*)(smem + 139264);                // [4 g][128 q] l partials
    float*    mbuf = (float*)(smem + 141312);                // [4 g][128 q] m partials

    const f32x4 zf = {0.f, 0.f, 0.f, 0.f};
    const _Float16 one_h = (_Float16)1.0f;
    const hv8 ones = { one_h, one_h, one_h, one_h, one_h, one_h, one_h, one_h };

    // q fragments, 4 groups of 16 q
    hv8 qf[4];
    #pragma unroll
    for (int X = 0; X < 4; ++X) {
        const int q = q0b + qw*64 + X*16 + l15;
        qf[X] = *reinterpret_cast<const hv8*>(
            bqT + ((size_t)n*NHW + q)*CQK + quad*8);
    }

    // kf base for this lane within this group's key range
    const _Float16* ckbase = ckT + ((size_t)(n*NHW + kg0 + l15))*CQK + quad*8;

    // online-softmax state: mneg[X] = -(running max of q=l15), in log2 units
    float mneg[4] = {0.f, 0.f, 0.f, 0.f};

    f32x4 acc[4][8];
    #pragma unroll
    for (int X = 0; X < 4; ++X)
        #pragma unroll
        for (int t = 0; t < 8; ++t) acc[X][t] = zf;
    f32x4 accL[4];
    #pragma unroll
    for (int X = 0; X < 4; ++X) accL[X] = zf;

    // ---- staging: 8 x global_load_lds per wave covers 64 co rows x 64 k.
    const int rl8 = lane >> 3;
    const _Float16* dvs = dv
        + (size_t)(n*CCH + co0 + qw*64 + rl8)*NHW + kg0 + 8*((lane & 7) ^ rl8);
    _Float16* ldsb = (_Float16*)(smem + (g << 14) + qw*8192);

    // swizzled V read offsets (halves)
    const int c0h = ((quad*16) ^ ((l15 & 7) << 4)) >> 1;
    const int c1h = ((64 + quad*16) ^ ((l15 & 7) << 4)) >> 1;

    // S^T/exp (online) for one key tile, all 4 q-groups -> pb
    auto softmax_tile = [&](const hv8* kf) {
        #pragma unroll
        for (int X = 0; X < 4; ++X) {
            const f32x4 minit = {mneg[X], mneg[X], mneg[X], mneg[X]};
            f32x4 s0 = __builtin_amdgcn_mfma_f32_16x16x32_f16(kf[0], qf[X], minit, 0, 0, 0);
            f32x4 s1 = __builtin_amdgcn_mfma_f32_16x16x32_f16(kf[1], qf[X], minit, 0, 0, 0);
            f32x4 s2 = __builtin_amdgcn_mfma_f32_16x16x32_f16(kf[2], qf[X], minit, 0, 0, 0);
            f32x4 s3 = __builtin_amdgcn_mfma_f32_16x16x32_f16(kf[3], qf[X], minit, 0, 0, 0);
            // tile max for q=l15 (reduce 16 regs, then across quads)
            float tm = fmaxf(
                fmaxf(fmaxf(fmaxf(s0[0], s0[1]), fmaxf(s0[2], s0[3])),
                      fmaxf(fmaxf(s1[0], s1[1]), fmaxf(s1[2], s1[3]))),
                fmaxf(fmaxf(fmaxf(s2[0], s2[1]), fmaxf(s2[2], s2[3])),
                      fmaxf(fmaxf(s3[0], s3[1]), fmaxf(s3[2], s3[3]))));
            tm = fmaxf(tm, __shfl_xor(tm, 16, 64));
            tm = fmaxf(tm, __shfl_xor(tm, 32, 64));
            const float upd = (tm > 8.0f) ? tm : 0.0f;
            if (__any(upd > 0.0f)) {
                const float sc = __builtin_amdgcn_exp2f(-upd);   // at q=l15
                // gather scales to acc's row mapping (q = quad*4+r)
                float s_r0 = __shfl(sc, quad*4 + 0, 64);
                float s_r1 = __shfl(sc, quad*4 + 1, 64);
                float s_r2 = __shfl(sc, quad*4 + 2, 64);
                float s_r3 = __shfl(sc, quad*4 + 3, 64);
                #pragma unroll
                for (int t = 0; t < 8; ++t) {
                    acc[X][t][0] *= s_r0; acc[X][t][1] *= s_r1;
                    acc[X][t][2] *= s_r2; acc[X][t][3] *= s_r3;
                }
                accL[X][0] *= s_r0; accL[X][1] *= s_r1;
                accL[X][2] *= s_r2; accL[X][3] *= s_r3;
                mneg[X] -= upd;
                s0[0] -= upd; s0[1] -= upd; s0[2] -= upd; s0[3] -= upd;
                s1[0] -= upd; s1[1] -= upd; s1[2] -= upd; s1[3] -= upd;
                s2[0] -= upd; s2[1] -= upd; s2[2] -= upd; s2[3] -= upd;
                s3[0] -= upd; s3[1] -= upd; s3[2] -= upd; s3[3] -= upd;
            }
            const f32x4 sv[4] = {s0, s1, s2, s3};
            #pragma unroll
            for (int f = 0; f < 4; ++f) {
                float p0 = __builtin_amdgcn_exp2f(sv[f][0]);
                float p1 = __builtin_amdgcn_exp2f(sv[f][1]);
                float p2 = __builtin_amdgcn_exp2f(sv[f][2]);
                float p3 = __builtin_amdgcn_exp2f(sv[f][3]);
                fv2 lo = __builtin_amdgcn_cvt_pkrtz(p0, p1);
                fv2 hi = __builtin_amdgcn_cvt_pkrtz(p2, p3);
                uint2 w;
                w.x = __builtin_bit_cast(unsigned, lo);
                w.y = __builtin_bit_cast(unsigned, hi);
                *reinterpret_cast<uint2*>(
                    pb + X*1152 + l15*72 + f*16 + quad*4) = w;
            }
        }
    };

    hv8 pf0[4], pf1[4];
    auto read_pf = [&]() {
        #pragma unroll
        for (int X = 0; X < 4; ++X) {
            pf0[X] = *reinterpret_cast<const hv8*>(pb + X*1152 + l15*72 + quad*8);
            pf1[X] = *reinterpret_cast<const hv8*>(pb + X*1152 + l15*72 + 32 + quad*8);
        }
    };

    auto stage = [&](int kt) {
        #pragma unroll
        for (int j = 0; j < 8; ++j)
            gll16(dvs + (size_t)(j*8)*NHW + kt*64, ldsb + (size_t)(j*8)*64);
    };

    auto load_kf = [&](int key0, hv8* kf) {
        #pragma unroll
        for (int f = 0; f < 4; ++f)
            kf[f] = *reinterpret_cast<const hv8*>(
                ckbase + (size_t)(key0 + f*16)*CQK);
    };

    // ---- prologue: stage V(0) via DMA, softmax(0), pf(0)
    {
        stage(0);
        hv8 kf0[4];
        load_kf(0, kf0);
        softmax_tile(kf0);
        read_pf();
    }
    __syncthreads();    // drains vmcnt -> V(0) resident

    for (int kt = 0; kt < 16; ++kt) {
        hv8 kfn[4];
        if (kt < 15) load_kf((kt + 1)*64, kfn);

        // ---- PV(kt): each V fragment feeds 4 q-groups
        #pragma unroll
        for (int t = 0; t < 8; ++t) {
            const _Float16* vr = vbuf + (t*16 + l15)*64;
            hv8 d0 = *reinterpret_cast<const hv8*>(vr + c0h);
            #pragma unroll
            for (int X = 0; X < 4; ++X)
                acc[X][t] = __builtin_amdgcn_mfma_f32_16x16x32_f16(
                    pf0[X], d0, acc[X][t], 0, 0, 0);
            hv8 d1 = *reinterpret_cast<const hv8*>(vr + c1h);
            #pragma unroll
            for (int X = 0; X < 4; ++X)
                acc[X][t] = __builtin_amdgcn_mfma_f32_16x16x32_f16(
                    pf1[X], d1, acc[X][t], 0, 0, 0);
        }
        #pragma unroll
        for (int X = 0; X < 4; ++X) {
            accL[X] = __builtin_amdgcn_mfma_f32_16x16x32_f16(pf0[X], ones, accL[X], 0, 0, 0);
            accL[X] = __builtin_amdgcn_mfma_f32_16x16x32_f16(pf1[X], ones, accL[X], 0, 0, 0);
        }

        if (kt < 15) {
            softmax_tile(kfn);          // p(kt+1) -> pb (own wave region)
            __syncthreads();            // all done reading V(kt)
            stage(kt + 1);              // DMA V(kt+1) into same buffer
            read_pf();                  // pf(kt+1) from pb (same-wave order)
            __syncthreads();            // drains vmcnt -> V(kt+1) resident
        }
    }

    // ---- align k-group partials to the common max, merge, epilogue
    if (lane < 16) {
        #pragma unroll
        for (int X = 0; X < 4; ++X)
            mbuf[g*128 + qw*64 + X*16 + l15] = -mneg[X];
    }
    __syncthreads();            // all waves past loop; mbuf complete

    {
        #pragma unroll
        for (int X = 0; X < 4; ++X) {
            const int qloc = qw*64 + X*16 + quad*4;
            float4 m0 = *reinterpret_cast<float4*>(&mbuf[0*128 + qloc]);
            float4 m1 = *reinterpret_cast<float4*>(&mbuf[1*128 + qloc]);
            float4 m2 = *reinterpret_cast<float4*>(&mbuf[2*128 + qloc]);
            float4 m3 = *reinterpret_cast<float4*>(&mbuf[3*128 + qloc]);
            float4 mm;
            mm.x = fmaxf(fmaxf(m0.x, m1.x), fmaxf(m2.x, m3.x));
            mm.y = fmaxf(fmaxf(m0.y, m1.y), fmaxf(m2.y, m3.y));
            mm.z = fmaxf(fmaxf(m0.z, m1.z), fmaxf(m2.z, m3.z));
            mm.w = fmaxf(fmaxf(m0.w, m1.w), fmaxf(m2.w, m3.w));
            float4 mo = (g == 0) ? m0 : (g == 1) ? m1 : (g == 2) ? m2 : m3;
            float sc0 = __builtin_amdgcn_exp2f(mo.x - mm.x);
            float sc1 = __builtin_amdgcn_exp2f(mo.y - mm.y);
            float sc2 = __builtin_amdgcn_exp2f(mo.z - mm.z);
            float sc3 = __builtin_amdgcn_exp2f(mo.w - mm.w);
            #pragma unroll
            for (int t = 0; t < 8; ++t) {
                acc[X][t][0] *= sc0; acc[X][t][1] *= sc1;
                acc[X][t][2] *= sc2; acc[X][t][3] *= sc3;
            }
            accL[X][0] *= sc0; accL[X][1] *= sc1;
            accL[X][2] *= sc2; accL[X][3] *= sc3;
        }
    }

    float* buf1 = (float*)smem;                   // [128 co][132 q]
    float* buf2 = (float*)(smem + 67584);
    const int qloc = qw*64 + quad*4;              // base within own 64-q half? (per-X below)

    if (l15 == 0) {
        #pragma unroll
        for (int X = 0; X < 4; ++X)
            *reinterpret_cast<float4*>(&lbuf[g*128 + qw*64 + X*16 + quad*4]) =
                *reinterpret_cast<float4*>(&accL[X]);
    }
    // Round A: g1 -> buf1, g3 -> buf2
    if (g == 1 || g == 3) {
        float* b = (g == 1) ? buf1 : buf2;
        #pragma unroll
        for (int X = 0; X < 4; ++X)
            #pragma unroll
            for (int t = 0; t < 8; ++t)
                *reinterpret_cast<float4*>(
                    &b[(t*16 + l15)*132 + qw*64 + X*16 + quad*4]) =
                    *reinterpret_cast<float4*>(&acc[X][t]);
    }
    __syncthreads();
    if (g == 0 || g == 2) {
        float* b = (g == 0) ? buf1 : buf2;
        #pragma unroll
        for (int X = 0; X < 4; ++X)
            #pragma unroll
            for (int t = 0; t < 8; ++t) {
                float4 p = *reinterpret_cast<float4*>(
                    &b[(t*16 + l15)*132 + qw*64 + X*16 + quad*4]);
                acc[X][t][0] += p.x; acc[X][t][1] += p.y;
                acc[X][t][2] += p.z; acc[X][t][3] += p.w;
            }
    }
    __syncthreads();
    // Round B: g2 -> buf1
    if (g == 2) {
        #pragma unroll
        for (int X = 0; X < 4; ++X)
            #pragma unroll
            for (int t = 0; t < 8; ++t)
                *reinterpret_cast<float4*>(
                    &buf1[(t*16 + l15)*132 + qw*64 + X*16 + quad*4]) =
                    *reinterpret_cast<float4*>(&acc[X][t]);
    }
    __syncthreads();
    if (g == 0) {
        const float alpha = alpha_p[0];
        #pragma unroll
        for (int X = 0; X < 4; ++X) {
            const int qlocX = qw*64 + X*16 + quad*4;
            #pragma unroll
            for (int t = 0; t < 8; ++t) {
                float4 p = *reinterpret_cast<float4*>(
                    &buf1[(t*16 + l15)*132 + qlocX]);
                acc[X][t][0] += p.x; acc[X][t][1] += p.y;
                acc[X][t][2] += p.z; acc[X][t][3] += p.w;
            }
            float4 l0 = *reinterpret_cast<float4*>(&lbuf[0*128 + qlocX]);
            float4 l1 = *reinterpret_cast<float4*>(&lbuf[1*128 + qlocX]);
            float4 l2 = *reinterpret_cast<float4*>(&lbuf[2*128 + qlocX]);
            float4 l3 = *reinterpret_cast<float4*>(&lbuf[3*128 + qlocX]);
            f32x4 rl;
            rl[0] = alpha / (l0.x + l1.x + l2.x + l3.x);
            rl[1] = alpha / (l0.y + l1.y + l2.y + l3.y);
            rl[2] = alpha / (l0.z + l1.z + l2.z + l3.z);
            rl[3] = alpha / (l0.w + l1.w + l2.w + l3.w);
            #pragma unroll
            for (int t = 0; t < 8; ++t) {
                const size_t off =
                    ((size_t)(n*CCH + co0 + t*16 + l15))*NHW + q0b + qlocX;
                float4 av = *reinterpret_cast<const float4*>(a + off);
                float4 o;
                o.x = acc[X][t][0]*rl[0] + av.x;
                o.y = acc[X][t][1]*rl[1] + av.y;
                o.z = acc[X][t][2]*rl[2] + av.z;
                o.w = acc[X][t][3]*rl[3] + av.w;
                *reinterpret_cast<float4*>(out + off) = o;
            }
        }
    }
}

extern "C" void kernel_launch(void* const* d_in, const int* in_sizes, int n_in,
                              void* d_out, int out_size, void* d_ws, size_t ws_size,
                              hipStream_t stream)
{
    const float* a    = (const float*)d_in[0];
    const float* b_w  = (const float*)d_in[1];
    const float* b_b  = (const float*)d_in[2];
    const float* c_w  = (const float*)d_in[3];
    const float* c_b  = (const float*)d_in[4];
    const float* d_w  = (const float*)d_in[5];
    const float* d_b  = (const float*)d_in[6];
    const float* alp  = (const float*)d_in[7];
    float* out = (float*)d_out;

    _Float16* bqT  = (_Float16*)d_ws;                 // [4][4096][32] fp16, 1 MB
    _Float16* ckT  = bqT + (size_t)4*NHW*CQK;         // [4][4096][32] fp16, 1 MB
    _Float16* dv   = ckT + (size_t)4*NHW*CQK;         // [4][256][4096] fp16, 8 MB
    _Float16* Wh   = dv + (size_t)4*CCH*NHW;          // [320][256] fp16, 160 KB

    prep_kernel<<<80, 256, 0, stream>>>(b_w, c_w, d_w, Wh);
    proj_kernel<<<512, 256, 0, stream>>>(a, Wh, b_b, c_b, d_b, bqT, ckT, dv);
    attn_kernel<<<256, 512, 0, stream>>>(bqT, ckT, dv, a, alp, out);
}